// Round 2
// baseline (1922.255 us; speedup 1.0000x reference)
//
#include <hip/hip_runtime.h>

using u16 = unsigned short;

constexpr int Bb = 8;
constexpr int Nn = 16384;
constexpr int Kk = 128;
constexpr int Cc = 128;
constexpr int Ll = 4;
constexpr int SPLIT = 32;
constexpr int LDA = 392;   // padded inner (385 -> 392)

__device__ __forceinline__ float b2f(u16 u) {
    union { unsigned int i; float f; } v; v.i = ((unsigned int)u) << 16; return v.f;
}
__device__ __forceinline__ u16 f2b(float f) {
    union { float f; unsigned int i; } v; v.f = f;
    unsigned int i = v.i;
    return (u16)((i + 0x7fffu + ((i >> 16) & 1u)) >> 16);
}
__device__ __forceinline__ void load8(const u16* p, float* o) {
    uint4 q = *(const uint4*)p;
    o[0] = b2f(q.x & 0xffffu); o[1] = b2f(q.x >> 16);
    o[2] = b2f(q.y & 0xffffu); o[3] = b2f(q.y >> 16);
    o[4] = b2f(q.z & 0xffffu); o[5] = b2f(q.z >> 16);
    o[6] = b2f(q.w & 0xffffu); o[7] = b2f(q.w >> 16);
}
__device__ __forceinline__ float gelu_f(float x) {
    return 0.5f * x * (1.0f + erff(x * 0.70710678118654752f));
}

// ---- dtype detection + input normalization ----
// node_mask is all ones: first u32 = 0x3F800000 (f32) or 0x3F803F80 (bf16).
__global__ void detect_kernel(const unsigned int* __restrict__ maskw, int* __restrict__ flag) {
    if (threadIdx.x == 0 && blockIdx.x == 0)
        *flag = ((maskw[0] & 0xFFFFu) != 0u) ? 1 : 0;   // 1 = inputs are bf16
}

struct SegTable {
    const void* src[16];
    u16* dst[16];
    int count[16];
};

__global__ __launch_bounds__(256) void convert_kernel(SegTable t, const int* __restrict__ flag) {
    const int f = *flag;
    const int stride = gridDim.x * 256;
    for (int seg = 0; seg < 16; ++seg) {
        const int cnt = t.count[seg];
        const void* s = t.src[seg];
        u16* d = t.dst[seg];
        for (int i = blockIdx.x * 256 + threadIdx.x; i < cnt; i += stride) {
            d[i] = f ? ((const u16*)s)[i] : f2b(((const float*)s)[i]);
        }
    }
}

// bcT[b,k,n] = cos(nodes[b,n,:].modes[k,:]) * mask ; bsT = sin(...) * mask
__global__ __launch_bounds__(256) void bases_kernel(
    const u16* __restrict__ nodes, const u16* __restrict__ modes,
    const u16* __restrict__ mask, u16* __restrict__ bcT, u16* __restrict__ bsT) {
    int n = blockIdx.x * 256 + threadIdx.x;
    int k = blockIdx.y, b = blockIdx.z;
    float m0 = b2f(modes[k * 2]), m1 = b2f(modes[k * 2 + 1]);
    float nx = b2f(nodes[((size_t)(b * Nn + n)) * 2]);
    float ny = b2f(nodes[((size_t)(b * Nn + n)) * 2 + 1]);
    float t = nx * m0 + ny * m1;
    float mk = b2f(mask[b * Nn + n]);
    float s, c;
    sincosf(t, &s, &c);
    size_t off = ((size_t)(b * Kk + k)) * Nn + n;
    bcT[off] = f2b(c * mk);
    bsT[off] = f2b(s * mk);
}

// h[b,c,n] = sum_d x[b,n,d]*fc0_w[d,c] + fc0_b[c] ; hw = h * node_weights
__global__ __launch_bounds__(256) void fc0_kernel(
    const u16* __restrict__ x, const u16* __restrict__ fc0_w,
    const u16* __restrict__ fc0_b, const u16* __restrict__ wn,
    u16* __restrict__ h, u16* __restrict__ hw) {
    int n = blockIdx.x * 256 + threadIdx.x;
    int c = blockIdx.y, b = blockIdx.z;
    const u16* xp = x + ((size_t)(b * Nn + n)) * 3;
    float acc = b2f(fc0_b[c]);
    acc += b2f(xp[0]) * b2f(fc0_w[0 * Cc + c]);
    acc += b2f(xp[1]) * b2f(fc0_w[1 * Cc + c]);
    acc += b2f(xp[2]) * b2f(fc0_w[2 * Cc + c]);
    size_t off = ((size_t)(b * Cc + c)) * Nn + n;
    h[off] = f2b(acc);
    hw[off] = f2b(acc * b2f(wn[b * Nn + n]));
}

// x0[b,c] = sum_n hw[b,c,n] * mask[b,n]
__global__ __launch_bounds__(256) void x0_kernel(
    const u16* __restrict__ hw, const u16* __restrict__ mask, float* __restrict__ x0) {
    int c = blockIdx.x, b = blockIdx.y;
    const u16* row = hw + ((size_t)(b * Cc + c)) * Nn;
    const u16* mrow = mask + (size_t)b * Nn;
    float acc = 0.f;
    for (int n = threadIdx.x; n < Nn; n += 256) acc += b2f(row[n]) * b2f(mrow[n]);
    __shared__ float red[4];
    for (int off = 32; off; off >>= 1) acc += __shfl_down(acc, off, 64);
    if ((threadIdx.x & 63) == 0) red[threadIdx.x >> 6] = acc;
    __syncthreads();
    if (threadIdx.x == 0) x0[b * Cc + c] = red[0] + red[1] + red[2] + red[3];
}

// partial projections: pxc[b,s,c,k] = sum_{n in chunk} hw[b,c,n]*bcT[b,k,n]; pps with bsT
__global__ __launch_bounds__(256) void proj_kernel(
    const u16* __restrict__ hw, const u16* __restrict__ bcT, const u16* __restrict__ bsT,
    float* __restrict__ pxc, float* __restrict__ pps) {
    int s = blockIdx.x;          // split index
    int kh = blockIdx.y;         // k half: 0/1
    int b = blockIdx.z;
    const int Nc = Nn / SPLIT;   // 512
    int nbase0 = s * Nc;
    int tx = threadIdx.x & 15;   // k = kh*64 + tx*4 + v
    int ty = threadIdx.x >> 4;   // c = ty*8 + u
    __shared__ float sA[32][132];   // [n][c]
    __shared__ float sBc[32][68];   // [n][k]
    __shared__ float sBs[32][68];
    float acc_c[8][4], acc_s[8][4];
    #pragma unroll
    for (int u = 0; u < 8; u++)
        #pragma unroll
        for (int v = 0; v < 4; v++) { acc_c[u][v] = 0.f; acc_s[u][v] = 0.f; }

    for (int chunk = 0; chunk < Nc / 32; ++chunk) {
        int nb = nbase0 + chunk * 32;
        __syncthreads();
        {   // stage hw: 128c x 32n
            int c = threadIdx.x & 127, nh = (threadIdx.x >> 7) * 16;
            const u16* p = hw + ((size_t)(b * Cc + c)) * Nn + nb + nh;
            float f[16];
            load8(p, f); load8(p + 8, f + 8);
            #pragma unroll
            for (int i = 0; i < 16; i++) sA[nh + i][c] = f[i];
        }
        {   // stage bcT/bsT: 64k x 32n (for this k half)
            int k = threadIdx.x & 63, ng = (threadIdx.x >> 6) * 8;
            size_t roff = ((size_t)(b * Kk + kh * 64 + k)) * Nn + nb + ng;
            float fc[8], fs[8];
            load8(bcT + roff, fc); load8(bsT + roff, fs);
            #pragma unroll
            for (int i = 0; i < 8; i++) { sBc[ng + i][k] = fc[i]; sBs[ng + i][k] = fs[i]; }
        }
        __syncthreads();
        #pragma unroll 4
        for (int j = 0; j < 32; j++) {
            float a0[8];
            *(float4*)&a0[0] = *(const float4*)&sA[j][ty * 8];
            *(float4*)&a0[4] = *(const float4*)&sA[j][ty * 8 + 4];
            float4 vc = *(const float4*)&sBc[j][tx * 4];
            float4 vs = *(const float4*)&sBs[j][tx * 4];
            #pragma unroll
            for (int u = 0; u < 8; u++) {
                acc_c[u][0] += a0[u] * vc.x; acc_c[u][1] += a0[u] * vc.y;
                acc_c[u][2] += a0[u] * vc.z; acc_c[u][3] += a0[u] * vc.w;
                acc_s[u][0] += a0[u] * vs.x; acc_s[u][1] += a0[u] * vs.y;
                acc_s[u][2] += a0[u] * vs.z; acc_s[u][3] += a0[u] * vs.w;
            }
        }
    }
    size_t base = ((size_t)((b * SPLIT + s) * Cc)) * Kk;
    #pragma unroll
    for (int u = 0; u < 8; u++) {
        int c = ty * 8 + u;
        size_t off = base + (size_t)c * Kk + kh * 64 + tx * 4;
        *(float4*)&pxc[off] = make_float4(acc_c[u][0], acc_c[u][1], acc_c[u][2], acc_c[u][3]);
        *(float4*)&pps[off] = make_float4(acc_s[u][0], acc_s[u][1], acc_s[u][2], acc_s[u][3]);
    }
}

__global__ __launch_bounds__(256) void reduce_kernel(
    const float* __restrict__ pxc, const float* __restrict__ pps,
    float* __restrict__ xc, float* __restrict__ ps) {
    int g = blockIdx.x * 256 + threadIdx.x;  // < B*C*K
    int b = g >> 14, r = g & 16383;
    const float* p1 = pxc + ((size_t)b * SPLIT) * 16384 + r;
    const float* p2 = pps + ((size_t)b * SPLIT) * 16384 + r;
    float a1 = 0.f, a2 = 0.f;
    #pragma unroll
    for (int s2 = 0; s2 < SPLIT; s2++) {
        a1 += p1[(size_t)s2 * 16384];
        a2 += p2[(size_t)s2 * 16384];
    }
    xc[g] = a1; ps[g] = a2;
}

// f0[b,o] = sum_i x0[b,i] * w0[l,i,o]
__global__ __launch_bounds__(128) void f0_kernel(
    const float* __restrict__ x0, const u16* __restrict__ w0, float* __restrict__ f0, int l) {
    int o = threadIdx.x, b = blockIdx.x;
    float a = 0.f;
    for (int i = 0; i < Cc; i++)
        a += x0[b * Cc + i] * b2f(w0[((size_t)(l * Cc + i)) * Cc + o]);
    f0[b * Cc + o] = a;
}

// fch[b,o,k] = sum_i xc*wc + ps*ws ; fsh[b,o,k] = sum_i xc*ws - ps*wc   (xs = -ps)
__global__ __launch_bounds__(128) void mix_kernel(
    const float* __restrict__ xc, const float* __restrict__ ps,
    const u16* __restrict__ wc, const u16* __restrict__ ws,
    float* __restrict__ fch, float* __restrict__ fsh, int l) {
    int k = threadIdx.x;
    int o0 = blockIdx.x * 8, b = blockIdx.y;
    float fc[8], fs[8];
    #pragma unroll
    for (int u = 0; u < 8; u++) { fc[u] = 0.f; fs[u] = 0.f; }
    for (int i = 0; i < Cc; i++) {
        float xcv = xc[(size_t)(b * Cc + i) * Kk + k];
        float psv = ps[(size_t)(b * Cc + i) * Kk + k];
        const u16* pw = wc + ((size_t)((l * Cc + i) * Cc + o0)) * Kk + k;
        const u16* qw = ws + ((size_t)((l * Cc + i) * Cc + o0)) * Kk + k;
        #pragma unroll
        for (int u = 0; u < 8; u++) {
            float wcv = b2f(pw[(size_t)u * Kk]);
            float wsv = b2f(qw[(size_t)u * Kk]);
            fc[u] += xcv * wcv + psv * wsv;
            fs[u] += xcv * wsv - psv * wcv;
        }
    }
    #pragma unroll
    for (int u = 0; u < 8; u++) {
        fch[(size_t)(b * Cc + o0 + u) * Kk + k] = fc[u];
        fsh[(size_t)(b * Cc + o0 + u) * Kk + k] = fs[u];
    }
}

// A[b,o,:] = [2*fc | -2*fs | conv_w[l,o,:] | f0 | zeros(pad)]
__global__ __launch_bounds__(256) void buildA_kernel(
    const float* __restrict__ fch, const float* __restrict__ fsh,
    const float* __restrict__ f0, const u16* __restrict__ conv_w,
    float* __restrict__ A, int l) {
    int b = blockIdx.x, o = blockIdx.y;
    float* row = A + ((size_t)(b * Cc + o)) * LDA;
    for (int kk = threadIdx.x; kk < LDA; kk += 256) {
        float v;
        if (kk < 128)      v = 2.f * fch[(size_t)(b * Cc + o) * Kk + kk];
        else if (kk < 256) v = -2.f * fsh[(size_t)(b * Cc + o) * Kk + (kk - 128)];
        else if (kk < 384) v = b2f(conv_w[(size_t)(l * Cc + o) * Cc + (kk - 256)]);
        else if (kk == 384) v = f0[b * Cc + o];
        else v = 0.f;
        row[kk] = v;
    }
}

// A[o,:] = [fc1_w^T | zeros]
__global__ __launch_bounds__(256) void buildA1_kernel(
    const u16* __restrict__ fc1_w, float* __restrict__ A) {
    int o = blockIdx.y;
    float* row = A + (size_t)o * LDA;
    for (int kk = threadIdx.x; kk < LDA; kk += 256)
        row[kk] = (kk < 128) ? b2f(fc1_w[kk * 128 + o]) : 0.f;
}

// Fused GEMM: out[b,o,n] = sum_kk A[b,o,kk] * Brow(kk)[b,n]  (+bias, opt gelu)
// Brow(kk): kk<e0 -> s0 ; kk<e1 -> s1 ; kk<e2 -> s2 ; else -> s3   (bf16, row stride N)
// EPI 0: gelu, write h and hw=h*wn   EPI 1: no gelu, write h   EPI 2: gelu, write h only
template <int EPI>
__global__ __launch_bounds__(256) void fuse_gemm(
    const float* __restrict__ A, long astrB, int inner, int nch,
    const u16* __restrict__ s0, long st0, const u16* __restrict__ s1, long st1,
    const u16* __restrict__ s2, long st2, const u16* __restrict__ s3, long st3,
    int e0, int e1, int e2,
    const u16* __restrict__ bias, const u16* __restrict__ wn,
    u16* __restrict__ outH, u16* __restrict__ outHW) {
    int nb = blockIdx.x * 64, b = blockIdx.y;
    int tx = threadIdx.x & 31;  // n = nb + tx*2 (+0/1)
    int ty = threadIdx.x >> 5;  // o = ty*16 + u
    __shared__ float sB[8][68];
    __shared__ float sA[8][132];
    float acc[16][2];
    #pragma unroll
    for (int u = 0; u < 16; u++) { acc[u][0] = 0.f; acc[u][1] = 0.f; }
    const float* Ab = A + (size_t)b * astrB;

    for (int ch = 0; ch < nch; ++ch) {
        int kk0 = ch * 8;
        __syncthreads();
        {   // stage B rows (2 elems/thread)
            int idx = threadIdx.x * 2;
            int r = idx >> 6, col = idx & 63;
            int kk = kk0 + r;
            float v0 = 0.f, v1 = 0.f;
            if (kk < inner) {
                const u16* p;
                if (kk < e0)      p = s0 + (size_t)b * st0 + (size_t)kk * Nn;
                else if (kk < e1) p = s1 + (size_t)b * st1 + (size_t)(kk - e0) * Nn;
                else if (kk < e2) p = s2 + (size_t)b * st2 + (size_t)(kk - e1) * Nn;
                else              p = s3 + (size_t)b * st3 + (size_t)(kk - e2) * Nn;
                v0 = b2f(p[nb + col]); v1 = b2f(p[nb + col + 1]);
            }
            sB[r][col] = v0; sB[r][col + 1] = v1;
        }
        {   // stage A (float4/thread), transposed into [j][o]
            int o = threadIdx.x >> 1, j0 = (threadIdx.x & 1) * 4;
            float4 a4 = *(const float4*)(Ab + (size_t)o * LDA + kk0 + j0);
            sA[j0 + 0][o] = a4.x; sA[j0 + 1][o] = a4.y;
            sA[j0 + 2][o] = a4.z; sA[j0 + 3][o] = a4.w;
        }
        __syncthreads();
        #pragma unroll
        for (int j = 0; j < 8; j++) {
            float b0 = sB[j][tx * 2], b1 = sB[j][tx * 2 + 1];
            #pragma unroll
            for (int uu = 0; uu < 4; ++uu) {
                float4 a4 = *(const float4*)&sA[j][ty * 16 + uu * 4];
                acc[uu * 4 + 0][0] += a4.x * b0; acc[uu * 4 + 0][1] += a4.x * b1;
                acc[uu * 4 + 1][0] += a4.y * b0; acc[uu * 4 + 1][1] += a4.y * b1;
                acc[uu * 4 + 2][0] += a4.z * b0; acc[uu * 4 + 2][1] += a4.z * b1;
                acc[uu * 4 + 3][0] += a4.w * b0; acc[uu * 4 + 3][1] += a4.w * b1;
            }
        }
    }
    int n0 = nb + tx * 2;
    float w0v = 1.f, w1v = 1.f;
    if (EPI == 0) {
        w0v = b2f(wn[(size_t)b * Nn + n0]);
        w1v = b2f(wn[(size_t)b * Nn + n0 + 1]);
    }
    #pragma unroll
    for (int u = 0; u < 16; u++) {
        int o = ty * 16 + u;
        float bv = b2f(bias[o]);
        float v0 = acc[u][0] + bv, v1 = acc[u][1] + bv;
        if (EPI == 0 || EPI == 2) { v0 = gelu_f(v0); v1 = gelu_f(v1); }
        size_t off = ((size_t)(b * Cc + o)) * Nn + n0;
        outH[off] = f2b(v0);
        outH[off + 1] = f2b(v1);
        if (EPI == 0) {
            outHW[off] = f2b(v0 * w0v);
            outHW[off + 1] = f2b(v1 * w1v);
        }
    }
}

// out[b,n] = (sum_f fc2_w[f]*t1[b,f,n] + fc2_b) * mask ; dtype per flag
__global__ __launch_bounds__(256) void fc2_kernel(
    const u16* __restrict__ t1, const u16* __restrict__ fc2_w, const u16* __restrict__ fc2_b,
    const u16* __restrict__ mask, void* __restrict__ out, const int* __restrict__ flag) {
    int n = blockIdx.x * 256 + threadIdx.x, b = blockIdx.y;
    const int f_bf16 = *flag;
    float a = 0.f;
    for (int f = 0; f < 128; f++)
        a += b2f(fc2_w[f]) * b2f(t1[((size_t)(b * 128 + f)) * Nn + n]);
    a += b2f(fc2_b[0]);
    a *= b2f(mask[(size_t)b * Nn + n]);
    size_t off = (size_t)b * Nn + n;
    if (f_bf16) ((u16*)out)[off] = f2b(a);
    else        ((float*)out)[off] = a;
}

extern "C" void kernel_launch(void* const* d_in, const int* in_sizes, int n_in,
                              void* d_out, int out_size, void* d_ws, size_t ws_size,
                              hipStream_t stream) {
    char* p = (char*)d_ws;
    auto alloc = [&](size_t bytes) { void* r = (void*)p; p += (bytes + 255) & ~(size_t)255; return r; };

    int* flag = (int*)alloc(256);

    // normalized bf16 copies of all 16 inputs
    SegTable tab;
    u16* nin[16];
    for (int i = 0; i < 16; i++) {
        int cnt = in_sizes[i];
        nin[i] = (u16*)alloc((size_t)cnt * 2);
        tab.src[i] = d_in[i];
        tab.dst[i] = nin[i];
        tab.count[i] = cnt;
    }
    const u16* x      = nin[0];
    const u16* nodes  = nin[1];
    const u16* mask   = nin[2];
    const u16* wn     = nin[3];
    const u16* modes  = nin[4];
    const u16* fc0_w  = nin[5];
    const u16* fc0_b  = nin[6];
    const u16* wc     = nin[7];
    const u16* ws_    = nin[8];
    const u16* w0     = nin[9];
    const u16* conv_w = nin[10];
    const u16* conv_b = nin[11];
    const u16* fc1_w  = nin[12];
    const u16* fc1_b  = nin[13];
    const u16* fc2_w  = nin[14];
    const u16* fc2_b  = nin[15];

    u16* bcT   = (u16*)alloc((size_t)Bb * Kk * Nn * 2);
    u16* bsT   = (u16*)alloc((size_t)Bb * Kk * Nn * 2);
    u16* h     = (u16*)alloc((size_t)Bb * Cc * Nn * 2);
    u16* hw    = (u16*)alloc((size_t)Bb * Cc * Nn * 2);
    float* pxc = (float*)alloc((size_t)Bb * SPLIT * Cc * Kk * 4);
    float* pps = (float*)alloc((size_t)Bb * SPLIT * Cc * Kk * 4);
    float* xc  = (float*)alloc((size_t)Bb * Cc * Kk * 4);
    float* ps  = (float*)alloc((size_t)Bb * Cc * Kk * 4);
    float* fch = (float*)alloc((size_t)Bb * Cc * Kk * 4);
    float* fsh = (float*)alloc((size_t)Bb * Cc * Kk * 4);
    float* x0  = (float*)alloc((size_t)Bb * Cc * 4);
    float* f0  = (float*)alloc((size_t)Bb * Cc * 4);
    float* Abuf = (float*)alloc((size_t)Bb * Cc * LDA * 4);

    detect_kernel<<<1, 64, 0, stream>>>((const unsigned int*)d_in[2], flag);
    convert_kernel<<<1024, 256, 0, stream>>>(tab, flag);

    bases_kernel<<<dim3(Nn / 256, Kk, Bb), 256, 0, stream>>>(nodes, modes, mask, bcT, bsT);
    fc0_kernel<<<dim3(Nn / 256, Cc, Bb), 256, 0, stream>>>(x, fc0_w, fc0_b, wn, h, hw);

    for (int l = 0; l < Ll; l++) {
        x0_kernel<<<dim3(Cc, Bb), 256, 0, stream>>>(hw, mask, x0);
        proj_kernel<<<dim3(SPLIT, 2, Bb), 256, 0, stream>>>(hw, bcT, bsT, pxc, pps);
        reduce_kernel<<<dim3((Bb * Cc * Kk) / 256), 256, 0, stream>>>(pxc, pps, xc, ps);
        f0_kernel<<<dim3(Bb), 128, 0, stream>>>(x0, w0, f0, l);
        mix_kernel<<<dim3(16, Bb), 128, 0, stream>>>(xc, ps, wc, ws_, fch, fsh, l);
        buildA_kernel<<<dim3(Bb, Cc), 256, 0, stream>>>(fch, fsh, f0, conv_w, Abuf, l);
        if (l < Ll - 1) {
            fuse_gemm<0><<<dim3(Nn / 64, Bb), 256, 0, stream>>>(
                Abuf, (long)Cc * LDA, 385, 49,
                bcT, (long)Kk * Nn, bsT, (long)Kk * Nn, h, (long)Cc * Nn, mask, (long)Nn,
                128, 256, 384, conv_b + l * Cc, wn, h, hw);
        } else {
            fuse_gemm<1><<<dim3(Nn / 64, Bb), 256, 0, stream>>>(
                Abuf, (long)Cc * LDA, 385, 49,
                bcT, (long)Kk * Nn, bsT, (long)Kk * Nn, h, (long)Cc * Nn, mask, (long)Nn,
                128, 256, 384, conv_b + l * Cc, wn, h, hw);
        }
    }

    buildA1_kernel<<<dim3(1, Cc), 256, 0, stream>>>(fc1_w, Abuf);
    fuse_gemm<2><<<dim3(Nn / 64, Bb), 256, 0, stream>>>(
        Abuf, 0L, 128, 16,
        h, (long)Cc * Nn, h, 0L, h, 0L, h, 0L,
        128, 128, 128, fc1_b, wn, hw, (u16*)nullptr);
    fc2_kernel<<<dim3(Nn / 256, Bb), 256, 0, stream>>>(hw, fc2_w, fc2_b, mask, d_out, flag);
}

// Round 4
// 1796.940 us; speedup vs baseline: 1.0697x; 1.0697x over previous
//
#include <hip/hip_runtime.h>

using u16 = unsigned short;
typedef short bf8 __attribute__((ext_vector_type(8)));
typedef float f4 __attribute__((ext_vector_type(4)));

constexpr int Bb = 8;
constexpr int Nn = 16384;
constexpr int Kk = 128;
constexpr int Cc = 128;
constexpr int Ll = 4;
constexpr int SPLIT = 32;
constexpr int BIGW = 384;   // big row: [bc(128) | bs(128) | h(128)]

__device__ __forceinline__ float b2f(u16 u) {
    union { unsigned int i; float f; } v; v.i = ((unsigned int)u) << 16; return v.f;
}
__device__ __forceinline__ u16 f2b(float f) {
    union { float f; unsigned int i; } v; v.f = f;
    unsigned int i = v.i;
    return (u16)((i + 0x7fffu + ((i >> 16) & 1u)) >> 16);
}
__device__ __forceinline__ float gelu_f(float x) {
    return 0.5f * x * (1.0f + erff(x * 0.70710678118654752f));
}

// ---- dtype detection + input normalization ----
__global__ void detect_kernel(const unsigned int* __restrict__ maskw, int* __restrict__ flag) {
    if (threadIdx.x == 0 && blockIdx.x == 0)
        *flag = ((maskw[0] & 0xFFFFu) != 0u) ? 1 : 0;   // 1 = inputs are bf16
}

struct SegTable {
    const void* src[16];
    u16* dst[16];
    int count[16];
};

__global__ __launch_bounds__(256) void convert_kernel(SegTable t, const int* __restrict__ flag) {
    const int f = *flag;
    const int stride = gridDim.x * 256;
    for (int seg = 0; seg < 16; ++seg) {
        const int cnt = t.count[seg];
        const void* s = t.src[seg];
        u16* d = t.dst[seg];
        for (int i = blockIdx.x * 256 + threadIdx.x; i < cnt; i += stride) {
            d[i] = f ? ((const u16*)s)[i] : f2b(((const float*)s)[i]);
        }
    }
}

// big[b][n][0:128]=cos*mask, [128:256]=sin*mask  (node-major, kk-contiguous)
__global__ __launch_bounds__(256) void bases_nk_kernel(
    const u16* __restrict__ nodes, const u16* __restrict__ modes,
    const u16* __restrict__ mask, u16* __restrict__ big) {
    int t = threadIdx.x;
    int nl = t >> 2, kp = t & 3;
    int n = blockIdx.x * 64 + nl, b = blockIdx.y;
    float nx = b2f(nodes[((size_t)(b * Nn + n)) * 2]);
    float ny = b2f(nodes[((size_t)(b * Nn + n)) * 2 + 1]);
    float mk = b2f(mask[b * Nn + n]);
    u16 cb[32] __attribute__((aligned(16)));
    u16 sb[32] __attribute__((aligned(16)));
    #pragma unroll
    for (int j = 0; j < 32; j++) {
        int k = kp * 32 + j;
        float m0 = b2f(modes[k * 2]), m1 = b2f(modes[k * 2 + 1]);
        float tt = nx * m0 + ny * m1;
        float s, c;
        sincosf(tt, &s, &c);
        cb[j] = f2b(c * mk);
        sb[j] = f2b(s * mk);
    }
    u16* row = big + ((size_t)b * Nn + n) * BIGW;
    #pragma unroll
    for (int i = 0; i < 4; i++) {
        *(uint4*)(row + kp * 32 + i * 8)       = *(const uint4*)(cb + i * 8);
        *(uint4*)(row + 128 + kp * 32 + i * 8) = *(const uint4*)(sb + i * 8);
    }
}

// h into big[b][n][256:384]; hw_cn[b][c][n] = h*wn
__global__ __launch_bounds__(256) void fc0_nk_kernel(
    const u16* __restrict__ x, const u16* __restrict__ fc0_w,
    const u16* __restrict__ fc0_b, const u16* __restrict__ wn,
    u16* __restrict__ big, u16* __restrict__ hw_cn) {
    int t = threadIdx.x;
    int nl = t >> 2, cp = t & 3;
    int n = blockIdx.x * 64 + nl, b = blockIdx.y;
    const u16* xp = x + ((size_t)(b * Nn + n)) * 3;
    float x0v = b2f(xp[0]), x1v = b2f(xp[1]), x2v = b2f(xp[2]);
    float wv = b2f(wn[b * Nn + n]);
    u16 hb[32] __attribute__((aligned(16)));
    #pragma unroll
    for (int j = 0; j < 32; j++) {
        int c = cp * 32 + j;
        float acc = b2f(fc0_b[c]);
        acc += x0v * b2f(fc0_w[0 * Cc + c]);
        acc += x1v * b2f(fc0_w[1 * Cc + c]);
        acc += x2v * b2f(fc0_w[2 * Cc + c]);
        hb[j] = f2b(acc);
        hw_cn[((size_t)(b * Cc + c)) * Nn + n] = f2b(acc * wv);
    }
    u16* row = big + ((size_t)b * Nn + n) * BIGW + 256 + cp * 32;
    #pragma unroll
    for (int i = 0; i < 4; i++) *(uint4*)(row + i * 8) = *(const uint4*)(hb + i * 8);
}

// x0[b,c] = sum_n hw[b,c,n]*mask[b,n]
__global__ __launch_bounds__(256) void x0_kernel(
    const u16* __restrict__ hw, const u16* __restrict__ mask, float* __restrict__ x0) {
    int c = blockIdx.x, b = blockIdx.y;
    const u16* row = hw + ((size_t)(b * Cc + c)) * Nn;
    const u16* mrow = mask + (size_t)b * Nn;
    float acc = 0.f;
    for (int n = threadIdx.x; n < Nn; n += 256) acc += b2f(row[n]) * b2f(mrow[n]);
    __shared__ float red[4];
    for (int off = 32; off; off >>= 1) acc += __shfl_down(acc, off, 64);
    if ((threadIdx.x & 63) == 0) red[threadIdx.x >> 6] = acc;
    __syncthreads();
    if (threadIdx.x == 0) x0[b * Cc + c] = red[0] + red[1] + red[2] + red[3];
}

// MFMA projection with on-the-fly bases.
// Wave w owns modes k = kh*64 + w*16 + lo (16 modes), all 128 channels.
// pxc[b,s,c,k] = sum_n hw[c,n]*cos(n.k)*mask ; pps with sin.
__global__ __launch_bounds__(256, 2) void proj_mfma(
    const u16* __restrict__ hw, const u16* __restrict__ nodes,
    const u16* __restrict__ modes, const u16* __restrict__ mask,
    float* __restrict__ pxc, float* __restrict__ pps) {
    int s = blockIdx.x, kh = blockIdx.y, b = blockIdx.z;
    int w = threadIdx.x >> 6, lane = threadIdx.x & 63;
    int lo = lane & 15, q = lane >> 4;
    int n0 = s * 512;
    int kmode = kh * 64 + w * 16 + lo;
    float m0 = b2f(modes[kmode * 2]), m1 = b2f(modes[kmode * 2 + 1]);
    const u16* ap[8];
    #pragma unroll
    for (int ct = 0; ct < 8; ct++)
        ap[ct] = hw + ((size_t)(b * Cc) + ct * 16 + lo) * Nn + n0 + q * 8;
    const u16* np = nodes + ((size_t)(b * Nn) + n0 + q * 8) * 2;
    const u16* mp = mask + (size_t)b * Nn + n0 + q * 8;
    f4 aC[8] = {}, aS[8] = {};
    for (int js = 0; js < 16; js++) {
        int off = js * 32;
        // compute B fragment: bases for mode kmode at n = n0 + off + q*8 + j
        uint4 nq0 = *(const uint4*)(np + off * 2);
        uint4 nq1 = *(const uint4*)(np + off * 2 + 8);
        uint4 mq  = *(const uint4*)(mp + off);
        float xs[8], ys[8], mk[8];
        xs[0] = b2f(nq0.x & 0xffffu); ys[0] = b2f(nq0.x >> 16);
        xs[1] = b2f(nq0.y & 0xffffu); ys[1] = b2f(nq0.y >> 16);
        xs[2] = b2f(nq0.z & 0xffffu); ys[2] = b2f(nq0.z >> 16);
        xs[3] = b2f(nq0.w & 0xffffu); ys[3] = b2f(nq0.w >> 16);
        xs[4] = b2f(nq1.x & 0xffffu); ys[4] = b2f(nq1.x >> 16);
        xs[5] = b2f(nq1.y & 0xffffu); ys[5] = b2f(nq1.y >> 16);
        xs[6] = b2f(nq1.z & 0xffffu); ys[6] = b2f(nq1.z >> 16);
        xs[7] = b2f(nq1.w & 0xffffu); ys[7] = b2f(nq1.w >> 16);
        mk[0] = b2f(mq.x & 0xffffu);  mk[1] = b2f(mq.x >> 16);
        mk[2] = b2f(mq.y & 0xffffu);  mk[3] = b2f(mq.y >> 16);
        mk[4] = b2f(mq.z & 0xffffu);  mk[5] = b2f(mq.z >> 16);
        mk[6] = b2f(mq.w & 0xffffu);  mk[7] = b2f(mq.w >> 16);
        u16 cf[8] __attribute__((aligned(16)));
        u16 sf[8] __attribute__((aligned(16)));
        #pragma unroll
        for (int j = 0; j < 8; j++) {
            float tt = xs[j] * m0 + ys[j] * m1;
            float sv_, cv_;
            sincosf(tt, &sv_, &cv_);
            cf[j] = f2b(cv_ * mk[j]);
            sf[j] = f2b(sv_ * mk[j]);
        }
        bf8 cv = *(const bf8*)cf;
        bf8 sv = *(const bf8*)sf;
        #pragma unroll
        for (int ct = 0; ct < 8; ct++) {
            bf8 av = *(const bf8*)(ap[ct] + off);
            aC[ct] = __builtin_amdgcn_mfma_f32_16x16x32_bf16(av, cv, aC[ct], 0, 0, 0);
            aS[ct] = __builtin_amdgcn_mfma_f32_16x16x32_bf16(av, sv, aS[ct], 0, 0, 0);
        }
    }
    size_t base = ((size_t)((b * SPLIT + s) * Cc)) * Kk;
    #pragma unroll
    for (int ct = 0; ct < 8; ct++) {
        #pragma unroll
        for (int r = 0; r < 4; r++) {
            int c = ct * 16 + q * 4 + r;
            pxc[base + (size_t)c * Kk + kmode] = aC[ct][r];
            pps[base + (size_t)c * Kk + kmode] = aS[ct][r];
        }
    }
}

__global__ __launch_bounds__(256) void reduce_kernel(
    const float* __restrict__ pxc, const float* __restrict__ pps,
    float* __restrict__ xc, float* __restrict__ ps) {
    int g = blockIdx.x * 256 + threadIdx.x;
    int b = g >> 14, r = g & 16383;
    const float* p1 = pxc + ((size_t)b * SPLIT) * 16384 + r;
    const float* p2 = pps + ((size_t)b * SPLIT) * 16384 + r;
    float a1 = 0.f, a2 = 0.f;
    #pragma unroll
    for (int s2 = 0; s2 < SPLIT; s2++) {
        a1 += p1[(size_t)s2 * 16384];
        a2 += p2[(size_t)s2 * 16384];
    }
    xc[g] = a1; ps[g] = a2;
}

__global__ __launch_bounds__(128) void f0_kernel(
    const float* __restrict__ x0, const u16* __restrict__ w0, float* __restrict__ f0p, int l) {
    int o = threadIdx.x, b = blockIdx.x;
    float a = 0.f;
    for (int i = 0; i < Cc; i++)
        a += x0[b * Cc + i] * b2f(w0[((size_t)(l * Cc + i)) * Cc + o]);
    f0p[b * Cc + o] = a;
}

// reads wc/ws_ raw from d_in (bf16 or f32 per flag)
__global__ __launch_bounds__(128) void mix_kernel(
    const float* __restrict__ xc, const float* __restrict__ ps,
    const void* __restrict__ wcraw, const void* __restrict__ wsraw,
    float* __restrict__ fch, float* __restrict__ fsh, int l,
    const int* __restrict__ flag) {
    const int f = *flag;
    int k = threadIdx.x;
    int o0 = blockIdx.x * 8, b = blockIdx.y;
    float fc[8], fs[8];
    #pragma unroll
    for (int u = 0; u < 8; u++) { fc[u] = 0.f; fs[u] = 0.f; }
    for (int i = 0; i < Cc; i++) {
        float xcv = xc[(size_t)(b * Cc + i) * Kk + k];
        float psv = ps[(size_t)(b * Cc + i) * Kk + k];
        size_t base = ((size_t)((l * Cc + i) * Cc + o0)) * Kk + k;
        #pragma unroll
        for (int u = 0; u < 8; u++) {
            size_t idx = base + (size_t)u * Kk;
            float wcv = f ? b2f(((const u16*)wcraw)[idx]) : ((const float*)wcraw)[idx];
            float wsv = f ? b2f(((const u16*)wsraw)[idx]) : ((const float*)wsraw)[idx];
            fc[u] += xcv * wcv + psv * wsv;
            fs[u] += xcv * wsv - psv * wcv;
        }
    }
    #pragma unroll
    for (int u = 0; u < 8; u++) {
        fch[(size_t)(b * Cc + o0 + u) * Kk + k] = fc[u];
        fsh[(size_t)(b * Cc + o0 + u) * Kk + k] = fs[u];
    }
}

// Ablk[b][ks(12)][o(128)][32] bf16: [2fc | -2fs | conv_w]
__global__ __launch_bounds__(256) void buildA_blk(
    const float* __restrict__ fch, const float* __restrict__ fsh,
    const u16* __restrict__ conv_w, u16* __restrict__ Ablk, int l) {
    int ks = blockIdx.x, b = blockIdx.y, t = threadIdx.x;
    int o = t >> 1, half = t & 1;
    u16 ov[16] __attribute__((aligned(16)));
    #pragma unroll
    for (int j = 0; j < 16; j++) {
        int kk = ks * 32 + half * 16 + j;
        float v;
        if (kk < 128)      v = 2.f * fch[((size_t)(b * Cc + o)) * Kk + kk];
        else if (kk < 256) v = -2.f * fsh[((size_t)(b * Cc + o)) * Kk + (kk - 128)];
        else               v = b2f(conv_w[((size_t)(l * Cc + o)) * Cc + (kk - 256)]);
        ov[j] = f2b(v);
    }
    u16* dst = Ablk + (((size_t)(b * 12 + ks)) * 128 + o) * 32 + half * 16;
    *(uint4*)dst = *(const uint4*)ov;
    *(uint4*)(dst + 8) = *(const uint4*)(ov + 8);
}

// Ablk1[ks(4)][o(128)][32] = fc1_w^T
__global__ __launch_bounds__(256) void buildA1_blk(
    const u16* __restrict__ fc1_w, u16* __restrict__ Ablk1) {
    int ks = blockIdx.x, t = threadIdx.x;
    int o = t >> 1, half = t & 1;
    u16 ov[16] __attribute__((aligned(16)));
    #pragma unroll
    for (int j = 0; j < 16; j++) {
        int kk = ks * 32 + half * 16 + j;
        ov[j] = fc1_w[kk * 128 + o];
    }
    u16* dst = Ablk1 + ((size_t)ks * 128 + o) * 32 + half * 16;
    *(uint4*)dst = *(const uint4*)ov;
    *(uint4*)(dst + 8) = *(const uint4*)(ov + 8);
}

// MFMA combine: D[o][n] = sum_kk Amat[o][kk]*big[n][KKOFF+kk]  (+f0*mask+bias, gelu)
// EPI 0: gelu, h->big, hw=h*wn->hwout. EPI 1: no gelu, h->big only. EPI 2: gelu, ->hwout only.
template <int EPI, int NKS, int KKOFF>
__global__ __launch_bounds__(256, 2) void combine_mfma(
    const u16* __restrict__ Ablk, long astr, u16* __restrict__ big,
    const float* __restrict__ f0p, const u16* __restrict__ bias,
    const u16* __restrict__ mask, const u16* __restrict__ wn,
    u16* __restrict__ hwout) {
    __shared__ u16 tr[4][16][136];
    int b = blockIdx.y;
    int w = threadIdx.x >> 6, lane = threadIdx.x & 63;
    int lo = lane & 15, q = lane >> 4;
    int nbw = blockIdx.x * 256 + w * 64;
    const u16* Ap = Ablk + (size_t)b * astr + (size_t)lo * 32 + q * 8;
    const u16* Bp[4];
    #pragma unroll
    for (int nt = 0; nt < 4; nt++)
        Bp[nt] = big + ((size_t)b * Nn + nbw + nt * 16 + lo) * BIGW + KKOFF + q * 8;
    f4 acc[8][4] = {};
    #pragma unroll
    for (int ks = 0; ks < NKS; ks++) {
        bf8 av[8], bv[4];
        #pragma unroll
        for (int ot = 0; ot < 8; ot++) av[ot] = *(const bf8*)(Ap + ks * 4096 + ot * 512);
        #pragma unroll
        for (int nt = 0; nt < 4; nt++) bv[nt] = *(const bf8*)(Bp[nt] + ks * 32);
        #pragma unroll
        for (int ot = 0; ot < 8; ot++)
            #pragma unroll
            for (int nt = 0; nt < 4; nt++)
                acc[ot][nt] = __builtin_amdgcn_mfma_f32_16x16x32_bf16(av[ot], bv[nt], acc[ot][nt], 0, 0, 0);
    }

    if (EPI == 2) {
        #pragma unroll
        for (int nt = 0; nt < 4; nt++) {
            int n = nbw + nt * 16 + lo;
            #pragma unroll
            for (int ot = 0; ot < 8; ot++)
                #pragma unroll
                for (int r = 0; r < 4; r++) {
                    int o = ot * 16 + q * 4 + r;
                    float v = acc[ot][nt][r] + b2f(bias[o]);
                    v = gelu_f(v);
                    hwout[((size_t)(b * Cc + o)) * Nn + n] = f2b(v);
                }
        }
    } else {
        for (int nt = 0; nt < 4; nt++) {
            int n = nbw + nt * 16 + lo;
            float mv = b2f(mask[(size_t)b * Nn + n]);
            float wv = (EPI == 0) ? b2f(wn[(size_t)b * Nn + n]) : 0.f;
            __syncthreads();
            #pragma unroll
            for (int ot = 0; ot < 8; ot++) {
                u16 hv[4] __attribute__((aligned(8)));
                #pragma unroll
                for (int r = 0; r < 4; r++) {
                    int o = ot * 16 + q * 4 + r;
                    float v = acc[ot][nt][r] + b2f(bias[o]) + f0p[b * Cc + o] * mv;
                    if (EPI == 0) v = gelu_f(v);
                    hv[r] = f2b(v);
                    if (EPI == 0)
                        hwout[((size_t)(b * Cc + o)) * Nn + n] = f2b(v * wv);
                }
                *(uint2*)&tr[w][lo][ot * 16 + q * 4] = *(const uint2*)hv;
            }
            __syncthreads();
            #pragma unroll
            for (int i = 0; i < 4; i++) {
                int id = i * 64 + lane;
                int nl2 = id >> 4, ch = id & 15;
                uint4 v4 = *(const uint4*)&tr[w][nl2][ch * 8];
                *(uint4*)&big[((size_t)b * Nn + nbw + nt * 16 + nl2) * BIGW + 256 + ch * 8] = v4;
            }
        }
    }
}

// out[b,n] = (sum_f fc2_w[f]*t1[b,f,n] + fc2_b) * mask ; dtype per flag
__global__ __launch_bounds__(256) void fc2_kernel(
    const u16* __restrict__ t1, const u16* __restrict__ fc2_w, const u16* __restrict__ fc2_b,
    const u16* __restrict__ mask, void* __restrict__ out, const int* __restrict__ flag) {
    int n = blockIdx.x * 256 + threadIdx.x, b = blockIdx.y;
    const int f_bf16 = *flag;
    float a = 0.f;
    for (int f = 0; f < 128; f++)
        a += b2f(fc2_w[f]) * b2f(t1[((size_t)(b * 128 + f)) * Nn + n]);
    a += b2f(fc2_b[0]);
    a *= b2f(mask[(size_t)b * Nn + n]);
    size_t off = (size_t)b * Nn + n;
    if (f_bf16) ((u16*)out)[off] = f2b(a);
    else        ((float*)out)[off] = a;
}

extern "C" void kernel_launch(void* const* d_in, const int* in_sizes, int n_in,
                              void* d_out, int out_size, void* d_ws, size_t ws_size,
                              hipStream_t stream) {
    char* p = (char*)d_ws;
    auto alloc = [&](size_t bytes) { void* r = (void*)p; p += (bytes + 255) & ~(size_t)255; return r; };

    int* flag = (int*)alloc(256);

    // normalized bf16 copies of inputs EXCEPT wc(7)/ws_(8) (read raw to save ws)
    SegTable tab;
    u16* nin[16];
    for (int i = 0; i < 16; i++) {
        tab.src[i] = d_in[i];
        if (i == 7 || i == 8) {
            nin[i] = (u16*)flag;   // never written (count 0)
            tab.dst[i] = nin[i];
            tab.count[i] = 0;
        } else {
            int cnt = in_sizes[i];
            nin[i] = (u16*)alloc((size_t)cnt * 2);
            tab.dst[i] = nin[i];
            tab.count[i] = cnt;
        }
    }
    const u16* x      = nin[0];
    const u16* nodes  = nin[1];
    const u16* mask   = nin[2];
    const u16* wn     = nin[3];
    const u16* modes  = nin[4];
    const u16* fc0_w  = nin[5];
    const u16* fc0_b  = nin[6];
    const u16* w0     = nin[9];
    const u16* conv_w = nin[10];
    const u16* conv_b = nin[11];
    const u16* fc1_w  = nin[12];
    const u16* fc1_b  = nin[13];
    const u16* fc2_w  = nin[14];
    const u16* fc2_b  = nin[15];

    u16* big    = (u16*)alloc((size_t)Bb * Nn * BIGW * 2);     // 100.7 MB
    u16* hw_cn  = (u16*)alloc((size_t)Bb * Cc * Nn * 2);       // 33.6 MB
    float* pxc  = (float*)alloc((size_t)Bb * SPLIT * Cc * Kk * 4);  // 16.8 MB
    float* pps  = (float*)alloc((size_t)Bb * SPLIT * Cc * Kk * 4);  // 16.8 MB
    float* xc   = (float*)alloc((size_t)Bb * Cc * Kk * 4);
    float* ps   = (float*)alloc((size_t)Bb * Cc * Kk * 4);
    float* fch  = (float*)alloc((size_t)Bb * Cc * Kk * 4);
    float* fsh  = (float*)alloc((size_t)Bb * Cc * Kk * 4);
    float* x0f  = (float*)alloc((size_t)Bb * Cc * 4);
    float* f0f  = (float*)alloc((size_t)Bb * Cc * 4);
    u16* Ablk   = (u16*)alloc((size_t)Bb * 12 * 128 * 32 * 2);
    u16* Ablk1  = (u16*)alloc((size_t)4 * 128 * 32 * 2);
    // total ws ≈ 173 MB (< 207 MB proven-safe in Round 2)

    const long ASTR = 12L * 128 * 32;

    detect_kernel<<<1, 64, 0, stream>>>((const unsigned int*)d_in[2], flag);
    convert_kernel<<<512, 256, 0, stream>>>(tab, flag);

    bases_nk_kernel<<<dim3(Nn / 64, Bb), 256, 0, stream>>>(nodes, modes, mask, big);
    fc0_nk_kernel<<<dim3(Nn / 64, Bb), 256, 0, stream>>>(x, fc0_w, fc0_b, wn, big, hw_cn);

    for (int l = 0; l < Ll; l++) {
        x0_kernel<<<dim3(Cc, Bb), 256, 0, stream>>>(hw_cn, mask, x0f);
        proj_mfma<<<dim3(SPLIT, 2, Bb), 256, 0, stream>>>(hw_cn, nodes, modes, mask, pxc, pps);
        reduce_kernel<<<dim3((Bb * Cc * Kk) / 256), 256, 0, stream>>>(pxc, pps, xc, ps);
        f0_kernel<<<dim3(Bb), 128, 0, stream>>>(x0f, w0, f0f, l);
        mix_kernel<<<dim3(16, Bb), 128, 0, stream>>>(xc, ps, d_in[7], d_in[8], fch, fsh, l, flag);
        buildA_blk<<<dim3(12, Bb), 256, 0, stream>>>(fch, fsh, conv_w, Ablk, l);
        if (l < Ll - 1) {
            combine_mfma<0, 12, 0><<<dim3(Nn / 256, Bb), 256, 0, stream>>>(
                Ablk, ASTR, big, f0f, conv_b + l * Cc, mask, wn, hw_cn);
        } else {
            combine_mfma<1, 12, 0><<<dim3(Nn / 256, Bb), 256, 0, stream>>>(
                Ablk, ASTR, big, f0f, conv_b + l * Cc, mask, wn, hw_cn);
        }
    }

    buildA1_blk<<<dim3(4), 256, 0, stream>>>(fc1_w, Ablk1);
    combine_mfma<2, 4, 256><<<dim3(Nn / 256, Bb), 256, 0, stream>>>(
        Ablk1, 0L, big, f0f, fc1_b, mask, wn, hw_cn);
    fc2_kernel<<<dim3(Nn / 256, Bb), 256, 0, stream>>>(hw_cn, fc2_w, fc2_b, mask, d_out, flag);
}

// Round 5
// 1382.043 us; speedup vs baseline: 1.3909x; 1.3002x over previous
//
#include <hip/hip_runtime.h>

using u16 = unsigned short;
typedef short bf8 __attribute__((ext_vector_type(8)));
typedef float f4 __attribute__((ext_vector_type(4)));

constexpr int Bb = 8;
constexpr int Nn = 16384;
constexpr int Kk = 128;
constexpr int Cc = 128;
constexpr int Ll = 4;
constexpr int SPLIT = 32;
constexpr int BIGW = 384;   // big row: [bc(128) | bs(128) | h(128)]

__device__ __forceinline__ float b2f(u16 u) {
    union { unsigned int i; float f; } v; v.i = ((unsigned int)u) << 16; return v.f;
}
__device__ __forceinline__ u16 f2b(float f) {
    union { float f; unsigned int i; } v; v.f = f;
    unsigned int i = v.i;
    return (u16)((i + 0x7fffu + ((i >> 16) & 1u)) >> 16);
}
__device__ __forceinline__ float gelu_f(float x) {
    return 0.5f * x * (1.0f + erff(x * 0.70710678118654752f));
}

// ---- dtype detection + input normalization ----
__global__ void detect_kernel(const unsigned int* __restrict__ maskw, int* __restrict__ flag) {
    if (threadIdx.x == 0 && blockIdx.x == 0)
        *flag = ((maskw[0] & 0xFFFFu) != 0u) ? 1 : 0;   // 1 = inputs are bf16
}

struct SegTable {
    const void* src[16];
    u16* dst[16];
    int count[16];
};

__global__ __launch_bounds__(256) void convert_kernel(SegTable t, const int* __restrict__ flag) {
    const int f = *flag;
    const int stride = gridDim.x * 256;
    for (int seg = 0; seg < 16; ++seg) {
        const int cnt = t.count[seg];
        const void* s = t.src[seg];
        u16* d = t.dst[seg];
        for (int i = blockIdx.x * 256 + threadIdx.x; i < cnt; i += stride) {
            d[i] = f ? ((const u16*)s)[i] : f2b(((const float*)s)[i]);
        }
    }
}

// big[b][n][0:128]=cos*mask, [128:256]=sin*mask  (node-major, kk-contiguous)
__global__ __launch_bounds__(256) void bases_nk_kernel(
    const u16* __restrict__ nodes, const u16* __restrict__ modes,
    const u16* __restrict__ mask, u16* __restrict__ big) {
    int t = threadIdx.x;
    int nl = t >> 2, kp = t & 3;
    int n = blockIdx.x * 64 + nl, b = blockIdx.y;
    float nx = b2f(nodes[((size_t)(b * Nn + n)) * 2]);
    float ny = b2f(nodes[((size_t)(b * Nn + n)) * 2 + 1]);
    float mk = b2f(mask[b * Nn + n]);
    u16 cb[32] __attribute__((aligned(16)));
    u16 sb[32] __attribute__((aligned(16)));
    #pragma unroll
    for (int j = 0; j < 32; j++) {
        int k = kp * 32 + j;
        float m0 = b2f(modes[k * 2]), m1 = b2f(modes[k * 2 + 1]);
        float tt = nx * m0 + ny * m1;
        float s, c;
        sincosf(tt, &s, &c);
        cb[j] = f2b(c * mk);
        sb[j] = f2b(s * mk);
    }
    u16* row = big + ((size_t)b * Nn + n) * BIGW;
    #pragma unroll
    for (int i = 0; i < 4; i++) {
        *(uint4*)(row + kp * 32 + i * 8)       = *(const uint4*)(cb + i * 8);
        *(uint4*)(row + 128 + kp * 32 + i * 8) = *(const uint4*)(sb + i * 8);
    }
}

// h into big[b][n][256:384]; hw_cn[b][c][n] = h*wn
__global__ __launch_bounds__(256) void fc0_nk_kernel(
    const u16* __restrict__ x, const u16* __restrict__ fc0_w,
    const u16* __restrict__ fc0_b, const u16* __restrict__ wn,
    u16* __restrict__ big, u16* __restrict__ hw_cn) {
    int t = threadIdx.x;
    int nl = t >> 2, cp = t & 3;
    int n = blockIdx.x * 64 + nl, b = blockIdx.y;
    const u16* xp = x + ((size_t)(b * Nn + n)) * 3;
    float x0v = b2f(xp[0]), x1v = b2f(xp[1]), x2v = b2f(xp[2]);
    float wv = b2f(wn[b * Nn + n]);
    u16 hb[32] __attribute__((aligned(16)));
    #pragma unroll
    for (int j = 0; j < 32; j++) {
        int c = cp * 32 + j;
        float acc = b2f(fc0_b[c]);
        acc += x0v * b2f(fc0_w[0 * Cc + c]);
        acc += x1v * b2f(fc0_w[1 * Cc + c]);
        acc += x2v * b2f(fc0_w[2 * Cc + c]);
        hb[j] = f2b(acc);
        hw_cn[((size_t)(b * Cc + c)) * Nn + n] = f2b(acc * wv);
    }
    u16* row = big + ((size_t)b * Nn + n) * BIGW + 256 + cp * 32;
    #pragma unroll
    for (int i = 0; i < 4; i++) *(uint4*)(row + i * 8) = *(const uint4*)(hb + i * 8);
}

// hw_cn[b][c][n] = big.h[b][n][c] * wn[b][n]   (64n x 128c tile via LDS)
__global__ __launch_bounds__(256) void hw_transpose(
    const u16* __restrict__ big, const u16* __restrict__ wn, u16* __restrict__ hw_cn) {
    __shared__ u16 lds[64][136];
    int nb = blockIdx.x * 64, b = blockIdx.y, t = threadIdx.x;
    #pragma unroll
    for (int i = 0; i < 4; i++) {
        int id = i * 256 + t;
        int row = id >> 4, ch = id & 15;
        int n = nb + row;
        uint4 v = *(const uint4*)&big[((size_t)b * Nn + n) * BIGW + 256 + ch * 8];
        float wv = b2f(wn[(size_t)b * Nn + n]);
        const u16* pv = (const u16*)&v;
        u16 o8[8] __attribute__((aligned(16)));
        #pragma unroll
        for (int j = 0; j < 8; j++) o8[j] = f2b(b2f(pv[j]) * wv);
        *(uint4*)&lds[row][ch * 8] = *(const uint4*)o8;
    }
    __syncthreads();
    int c = t >> 1, half = t & 1;
    u16 outv[32] __attribute__((aligned(16)));
    #pragma unroll
    for (int j = 0; j < 32; j++) outv[j] = lds[half * 32 + j][c];
    u16* dst = hw_cn + ((size_t)(b * Cc + c)) * Nn + nb + half * 32;
    #pragma unroll
    for (int i = 0; i < 4; i++) *(uint4*)(dst + i * 8) = *(const uint4*)(outv + i * 8);
}

// x0[b,c] = sum_n hw[b,c,n]*mask[b,n]
__global__ __launch_bounds__(256) void x0_kernel(
    const u16* __restrict__ hw, const u16* __restrict__ mask, float* __restrict__ x0) {
    int c = blockIdx.x, b = blockIdx.y;
    const u16* row = hw + ((size_t)(b * Cc + c)) * Nn;
    const u16* mrow = mask + (size_t)b * Nn;
    float acc = 0.f;
    for (int n = threadIdx.x; n < Nn; n += 256) acc += b2f(row[n]) * b2f(mrow[n]);
    __shared__ float red[4];
    for (int off = 32; off; off >>= 1) acc += __shfl_down(acc, off, 64);
    if ((threadIdx.x & 63) == 0) red[threadIdx.x >> 6] = acc;
    __syncthreads();
    if (threadIdx.x == 0) x0[b * Cc + c] = red[0] + red[1] + red[2] + red[3];
}

// MFMA projection with on-the-fly bases.
__global__ __launch_bounds__(256) void proj_mfma(
    const u16* __restrict__ hw, const u16* __restrict__ nodes,
    const u16* __restrict__ modes, const u16* __restrict__ mask,
    float* __restrict__ pxc, float* __restrict__ pps) {
    int s = blockIdx.x, kh = blockIdx.y, b = blockIdx.z;
    int w = threadIdx.x >> 6, lane = threadIdx.x & 63;
    int lo = lane & 15, q = lane >> 4;
    int n0 = s * 512;
    int kmode = kh * 64 + w * 16 + lo;
    float m0 = b2f(modes[kmode * 2]), m1 = b2f(modes[kmode * 2 + 1]);
    const u16* ap[8];
    #pragma unroll
    for (int ct = 0; ct < 8; ct++)
        ap[ct] = hw + ((size_t)(b * Cc) + ct * 16 + lo) * Nn + n0 + q * 8;
    const u16* np = nodes + ((size_t)(b * Nn) + n0 + q * 8) * 2;
    const u16* mp = mask + (size_t)b * Nn + n0 + q * 8;
    f4 aC[8] = {}, aS[8] = {};
    for (int js = 0; js < 16; js++) {
        int off = js * 32;
        uint4 nq0 = *(const uint4*)(np + off * 2);
        uint4 nq1 = *(const uint4*)(np + off * 2 + 8);
        uint4 mq  = *(const uint4*)(mp + off);
        float xs[8], ys[8], mk[8];
        xs[0] = b2f(nq0.x & 0xffffu); ys[0] = b2f(nq0.x >> 16);
        xs[1] = b2f(nq0.y & 0xffffu); ys[1] = b2f(nq0.y >> 16);
        xs[2] = b2f(nq0.z & 0xffffu); ys[2] = b2f(nq0.z >> 16);
        xs[3] = b2f(nq0.w & 0xffffu); ys[3] = b2f(nq0.w >> 16);
        xs[4] = b2f(nq1.x & 0xffffu); ys[4] = b2f(nq1.x >> 16);
        xs[5] = b2f(nq1.y & 0xffffu); ys[5] = b2f(nq1.y >> 16);
        xs[6] = b2f(nq1.z & 0xffffu); ys[6] = b2f(nq1.z >> 16);
        xs[7] = b2f(nq1.w & 0xffffu); ys[7] = b2f(nq1.w >> 16);
        mk[0] = b2f(mq.x & 0xffffu);  mk[1] = b2f(mq.x >> 16);
        mk[2] = b2f(mq.y & 0xffffu);  mk[3] = b2f(mq.y >> 16);
        mk[4] = b2f(mq.z & 0xffffu);  mk[5] = b2f(mq.z >> 16);
        mk[6] = b2f(mq.w & 0xffffu);  mk[7] = b2f(mq.w >> 16);
        u16 cf[8] __attribute__((aligned(16)));
        u16 sf[8] __attribute__((aligned(16)));
        #pragma unroll
        for (int j = 0; j < 8; j++) {
            float tt = xs[j] * m0 + ys[j] * m1;
            float sv_, cv_;
            sincosf(tt, &sv_, &cv_);
            cf[j] = f2b(cv_ * mk[j]);
            sf[j] = f2b(sv_ * mk[j]);
        }
        bf8 cv = *(const bf8*)cf;
        bf8 sv = *(const bf8*)sf;
        #pragma unroll
        for (int ct = 0; ct < 8; ct++) {
            bf8 av = *(const bf8*)(ap[ct] + off);
            aC[ct] = __builtin_amdgcn_mfma_f32_16x16x32_bf16(av, cv, aC[ct], 0, 0, 0);
            aS[ct] = __builtin_amdgcn_mfma_f32_16x16x32_bf16(av, sv, aS[ct], 0, 0, 0);
        }
    }
    size_t base = ((size_t)((b * SPLIT + s) * Cc)) * Kk;
    #pragma unroll
    for (int ct = 0; ct < 8; ct++) {
        #pragma unroll
        for (int r = 0; r < 4; r++) {
            int c = ct * 16 + q * 4 + r;
            pxc[base + (size_t)c * Kk + kmode] = aC[ct][r];
            pps[base + (size_t)c * Kk + kmode] = aS[ct][r];
        }
    }
}

__global__ __launch_bounds__(256) void reduce_kernel(
    const float* __restrict__ pxc, const float* __restrict__ pps,
    float* __restrict__ xc, float* __restrict__ ps) {
    int g = blockIdx.x * 256 + threadIdx.x;
    int b = g >> 14, r = g & 16383;
    const float* p1 = pxc + ((size_t)b * SPLIT) * 16384 + r;
    const float* p2 = pps + ((size_t)b * SPLIT) * 16384 + r;
    float a1 = 0.f, a2 = 0.f;
    #pragma unroll
    for (int s2 = 0; s2 < SPLIT; s2++) {
        a1 += p1[(size_t)s2 * 16384];
        a2 += p2[(size_t)s2 * 16384];
    }
    xc[g] = a1; ps[g] = a2;
}

__global__ __launch_bounds__(128) void f0_kernel(
    const float* __restrict__ x0, const u16* __restrict__ w0, float* __restrict__ f0p, int l) {
    int o = threadIdx.x, b = blockIdx.x;
    float a = 0.f;
    for (int i = 0; i < Cc; i++)
        a += x0[b * Cc + i] * b2f(w0[((size_t)(l * Cc + i)) * Cc + o]);
    f0p[b * Cc + o] = a;
}

// reads wc/ws_ raw from d_in (bf16 or f32 per flag)
__global__ __launch_bounds__(128) void mix_kernel(
    const float* __restrict__ xc, const float* __restrict__ ps,
    const void* __restrict__ wcraw, const void* __restrict__ wsraw,
    float* __restrict__ fch, float* __restrict__ fsh, int l,
    const int* __restrict__ flag) {
    const int f = *flag;
    int k = threadIdx.x;
    int o0 = blockIdx.x * 8, b = blockIdx.y;
    float fc[8], fs[8];
    #pragma unroll
    for (int u = 0; u < 8; u++) { fc[u] = 0.f; fs[u] = 0.f; }
    for (int i = 0; i < Cc; i++) {
        float xcv = xc[(size_t)(b * Cc + i) * Kk + k];
        float psv = ps[(size_t)(b * Cc + i) * Kk + k];
        size_t base = ((size_t)((l * Cc + i) * Cc + o0)) * Kk + k;
        #pragma unroll
        for (int u = 0; u < 8; u++) {
            size_t idx = base + (size_t)u * Kk;
            float wcv = f ? b2f(((const u16*)wcraw)[idx]) : ((const float*)wcraw)[idx];
            float wsv = f ? b2f(((const u16*)wsraw)[idx]) : ((const float*)wsraw)[idx];
            fc[u] += xcv * wcv + psv * wsv;
            fs[u] += xcv * wsv - psv * wcv;
        }
    }
    #pragma unroll
    for (int u = 0; u < 8; u++) {
        fch[(size_t)(b * Cc + o0 + u) * Kk + k] = fc[u];
        fsh[(size_t)(b * Cc + o0 + u) * Kk + k] = fs[u];
    }
}

// Ablk[b][ks(12)][o(128)][32] bf16: [2fc | -2fs | conv_w]
__global__ __launch_bounds__(256) void buildA_blk(
    const float* __restrict__ fch, const float* __restrict__ fsh,
    const u16* __restrict__ conv_w, u16* __restrict__ Ablk, int l) {
    int ks = blockIdx.x, b = blockIdx.y, t = threadIdx.x;
    int o = t >> 1, half = t & 1;
    u16 ov[16] __attribute__((aligned(16)));
    #pragma unroll
    for (int j = 0; j < 16; j++) {
        int kk = ks * 32 + half * 16 + j;
        float v;
        if (kk < 128)      v = 2.f * fch[((size_t)(b * Cc + o)) * Kk + kk];
        else if (kk < 256) v = -2.f * fsh[((size_t)(b * Cc + o)) * Kk + (kk - 128)];
        else               v = b2f(conv_w[((size_t)(l * Cc + o)) * Cc + (kk - 256)]);
        ov[j] = f2b(v);
    }
    u16* dst = Ablk + (((size_t)(b * 12 + ks)) * 128 + o) * 32 + half * 16;
    *(uint4*)dst = *(const uint4*)ov;
    *(uint4*)(dst + 8) = *(const uint4*)(ov + 8);
}

// Ablk1[ks(4)][o(128)][32] = fc1_w^T
__global__ __launch_bounds__(256) void buildA1_blk(
    const u16* __restrict__ fc1_w, u16* __restrict__ Ablk1) {
    int ks = blockIdx.x, t = threadIdx.x;
    int o = t >> 1, half = t & 1;
    u16 ov[16] __attribute__((aligned(16)));
    #pragma unroll
    for (int j = 0; j < 16; j++) {
        int kk = ks * 32 + half * 16 + j;
        ov[j] = fc1_w[kk * 128 + o];
    }
    u16* dst = Ablk1 + ((size_t)ks * 128 + o) * 32 + half * 16;
    *(uint4*)dst = *(const uint4*)ov;
    *(uint4*)(dst + 8) = *(const uint4*)(ov + 8);
}

// MFMA combine v2: block 128o x 128n, wave 128o x 32n, acc[8][2] (64 VGPR).
// EPI 0: +f0*mask+bias, gelu, write big.h (LDS transpose, full-line)
// EPI 1: same, no gelu
// EPI 2: +bias, gelu, fused fc2 dot + cross-lane reduce -> final out
template <int EPI, int NKS, int KKOFF>
__global__ __launch_bounds__(256) void combine_mfma(
    const u16* __restrict__ Ablk, long astr, u16* __restrict__ big,
    const float* __restrict__ f0p, const u16* __restrict__ bias,
    const u16* __restrict__ mask,
    const u16* __restrict__ fc2w, const u16* __restrict__ fc2b,
    void* __restrict__ out, const int* __restrict__ flag) {
    __shared__ u16 tr[4][16][136];
    int b = blockIdx.y;
    int w = threadIdx.x >> 6, lane = threadIdx.x & 63;
    int lo = lane & 15, q = lane >> 4;
    int nbw = blockIdx.x * 128 + w * 32;
    const u16* Ap = Ablk + (size_t)b * astr + (size_t)lo * 32 + q * 8;
    const u16* Bp[2];
    #pragma unroll
    for (int nt = 0; nt < 2; nt++)
        Bp[nt] = big + ((size_t)b * Nn + nbw + nt * 16 + lo) * BIGW + KKOFF + q * 8;
    f4 acc[8][2] = {};
    #pragma unroll
    for (int ks = 0; ks < NKS; ks++) {
        bf8 av[8], bv[2];
        #pragma unroll
        for (int ot = 0; ot < 8; ot++) av[ot] = *(const bf8*)(Ap + ks * 4096 + ot * 512);
        #pragma unroll
        for (int nt = 0; nt < 2; nt++) bv[nt] = *(const bf8*)(Bp[nt] + ks * 32);
        #pragma unroll
        for (int ot = 0; ot < 8; ot++)
            #pragma unroll
            for (int nt = 0; nt < 2; nt++)
                acc[ot][nt] = __builtin_amdgcn_mfma_f32_16x16x32_bf16(av[ot], bv[nt], acc[ot][nt], 0, 0, 0);
    }

    if (EPI == 2) {
        const int f_bf16 = *flag;
        float bv2 = b2f(fc2b[0]);
        #pragma unroll
        for (int nt = 0; nt < 2; nt++) {
            int n = nbw + nt * 16 + lo;
            float s = 0.f;
            #pragma unroll
            for (int ot = 0; ot < 8; ot++)
                #pragma unroll
                for (int r = 0; r < 4; r++) {
                    int o = ot * 16 + q * 4 + r;
                    float v = acc[ot][nt][r] + b2f(bias[o]);
                    v = gelu_f(v);
                    s += b2f(fc2w[o]) * v;
                }
            s += __shfl_xor(s, 16, 64);
            s += __shfl_xor(s, 32, 64);
            s = (s + bv2) * b2f(mask[(size_t)b * Nn + n]);
            if (q == 0) {
                size_t off = (size_t)b * Nn + n;
                if (f_bf16) ((u16*)out)[off] = f2b(s);
                else        ((float*)out)[off] = s;
            }
        }
    } else {
        #pragma unroll
        for (int nt = 0; nt < 2; nt++) {
            int n = nbw + nt * 16 + lo;
            float mv = b2f(mask[(size_t)b * Nn + n]);
            __syncthreads();
            #pragma unroll
            for (int ot = 0; ot < 8; ot++) {
                u16 hv[4] __attribute__((aligned(8)));
                #pragma unroll
                for (int r = 0; r < 4; r++) {
                    int o = ot * 16 + q * 4 + r;
                    float v = acc[ot][nt][r] + b2f(bias[o]) + f0p[b * Cc + o] * mv;
                    if (EPI == 0) v = gelu_f(v);
                    hv[r] = f2b(v);
                }
                *(uint2*)&tr[w][lo][ot * 16 + q * 4] = *(const uint2*)hv;
            }
            __syncthreads();
            #pragma unroll
            for (int i = 0; i < 4; i++) {
                int id = i * 64 + lane;
                int nl2 = id >> 4, ch = id & 15;
                uint4 v4 = *(const uint4*)&tr[w][nl2][ch * 8];
                *(uint4*)&big[((size_t)b * Nn + nbw + nt * 16 + nl2) * BIGW + 256 + ch * 8] = v4;
            }
        }
    }
}

extern "C" void kernel_launch(void* const* d_in, const int* in_sizes, int n_in,
                              void* d_out, int out_size, void* d_ws, size_t ws_size,
                              hipStream_t stream) {
    char* p = (char*)d_ws;
    auto alloc = [&](size_t bytes) { void* r = (void*)p; p += (bytes + 255) & ~(size_t)255; return r; };

    int* flag = (int*)alloc(256);

    // normalized bf16 copies of inputs EXCEPT wc(7)/ws_(8) (read raw to save ws)
    SegTable tab;
    u16* nin[16];
    for (int i = 0; i < 16; i++) {
        tab.src[i] = d_in[i];
        if (i == 7 || i == 8) {
            nin[i] = (u16*)flag;
            tab.dst[i] = nin[i];
            tab.count[i] = 0;
        } else {
            int cnt = in_sizes[i];
            nin[i] = (u16*)alloc((size_t)cnt * 2);
            tab.dst[i] = nin[i];
            tab.count[i] = cnt;
        }
    }
    const u16* x      = nin[0];
    const u16* nodes  = nin[1];
    const u16* mask   = nin[2];
    const u16* wn     = nin[3];
    const u16* modes  = nin[4];
    const u16* fc0_w  = nin[5];
    const u16* fc0_b  = nin[6];
    const u16* w0     = nin[9];
    const u16* conv_w = nin[10];
    const u16* conv_b = nin[11];
    const u16* fc1_w  = nin[12];
    const u16* fc1_b  = nin[13];
    const u16* fc2_w  = nin[14];
    const u16* fc2_b  = nin[15];

    u16* big    = (u16*)alloc((size_t)Bb * Nn * BIGW * 2);
    u16* hw_cn  = (u16*)alloc((size_t)Bb * Cc * Nn * 2);
    float* pxc  = (float*)alloc((size_t)Bb * SPLIT * Cc * Kk * 4);
    float* pps  = (float*)alloc((size_t)Bb * SPLIT * Cc * Kk * 4);
    float* xc   = (float*)alloc((size_t)Bb * Cc * Kk * 4);
    float* ps   = (float*)alloc((size_t)Bb * Cc * Kk * 4);
    float* fch  = (float*)alloc((size_t)Bb * Cc * Kk * 4);
    float* fsh  = (float*)alloc((size_t)Bb * Cc * Kk * 4);
    float* x0f  = (float*)alloc((size_t)Bb * Cc * 4);
    float* f0f  = (float*)alloc((size_t)Bb * Cc * 4);
    u16* Ablk   = (u16*)alloc((size_t)Bb * 12 * 128 * 32 * 2);
    u16* Ablk1  = (u16*)alloc((size_t)4 * 128 * 32 * 2);

    const long ASTR = 12L * 128 * 32;

    detect_kernel<<<1, 64, 0, stream>>>((const unsigned int*)d_in[2], flag);
    convert_kernel<<<512, 256, 0, stream>>>(tab, flag);

    bases_nk_kernel<<<dim3(Nn / 64, Bb), 256, 0, stream>>>(nodes, modes, mask, big);
    fc0_nk_kernel<<<dim3(Nn / 64, Bb), 256, 0, stream>>>(x, fc0_w, fc0_b, wn, big, hw_cn);

    for (int l = 0; l < Ll; l++) {
        x0_kernel<<<dim3(Cc, Bb), 256, 0, stream>>>(hw_cn, mask, x0f);
        proj_mfma<<<dim3(SPLIT, 2, Bb), 256, 0, stream>>>(hw_cn, nodes, modes, mask, pxc, pps);
        reduce_kernel<<<dim3((Bb * Cc * Kk) / 256), 256, 0, stream>>>(pxc, pps, xc, ps);
        f0_kernel<<<dim3(Bb), 128, 0, stream>>>(x0f, w0, f0f, l);
        mix_kernel<<<dim3(16, Bb), 128, 0, stream>>>(xc, ps, d_in[7], d_in[8], fch, fsh, l, flag);
        buildA_blk<<<dim3(12, Bb), 256, 0, stream>>>(fch, fsh, conv_w, Ablk, l);
        if (l < Ll - 1) {
            combine_mfma<0, 12, 0><<<dim3(Nn / 128, Bb), 256, 0, stream>>>(
                Ablk, ASTR, big, f0f, conv_b + l * Cc, mask, fc2_w, fc2_b, d_out, flag);
            hw_transpose<<<dim3(Nn / 64, Bb), 256, 0, stream>>>(big, wn, hw_cn);
        } else {
            combine_mfma<1, 12, 0><<<dim3(Nn / 128, Bb), 256, 0, stream>>>(
                Ablk, ASTR, big, f0f, conv_b + l * Cc, mask, fc2_w, fc2_b, d_out, flag);
        }
    }

    buildA1_blk<<<dim3(4), 256, 0, stream>>>(fc1_w, Ablk1);
    combine_mfma<2, 4, 256><<<dim3(Nn / 128, Bb), 256, 0, stream>>>(
        Ablk1, 0L, big, f0f, fc1_b, mask, fc2_w, fc2_b, d_out, flag);
}

// Round 6
// 904.346 us; speedup vs baseline: 2.1256x; 1.5282x over previous
//
#include <hip/hip_runtime.h>

using u16 = unsigned short;
typedef short bf8 __attribute__((ext_vector_type(8)));
typedef float f4 __attribute__((ext_vector_type(4)));

constexpr int Bb = 8;
constexpr int Nn = 16384;
constexpr int Kk = 128;
constexpr int Cc = 128;
constexpr int Ll = 4;
constexpr int SPLIT = 32;
constexpr int BIGW = 384;   // big row: [bc(128) | bs(128) | h(128)]

__device__ __forceinline__ float b2f(u16 u) {
    union { unsigned int i; float f; } v; v.i = ((unsigned int)u) << 16; return v.f;
}
__device__ __forceinline__ u16 f2b(float f) {
    union { float f; unsigned int i; } v; v.f = f;
    unsigned int i = v.i;
    return (u16)((i + 0x7fffu + ((i >> 16) & 1u)) >> 16);
}
__device__ __forceinline__ float gelu_f(float x) {
    return 0.5f * x * (1.0f + erff(x * 0.70710678118654752f));
}

// ---- dtype detection + input normalization ----
__global__ void detect_kernel(const unsigned int* __restrict__ maskw, int* __restrict__ flag) {
    if (threadIdx.x == 0 && blockIdx.x == 0)
        *flag = ((maskw[0] & 0xFFFFu) != 0u) ? 1 : 0;   // 1 = inputs are bf16
}

struct SegTable {
    const void* src[16];
    u16* dst[16];
    int count[16];
};

__global__ __launch_bounds__(256) void convert_kernel(SegTable t, const int* __restrict__ flag) {
    const int f = *flag;
    const int stride = gridDim.x * 256;
    for (int seg = 0; seg < 16; ++seg) {
        const int cnt = t.count[seg];
        const void* s = t.src[seg];
        u16* d = t.dst[seg];
        for (int i = blockIdx.x * 256 + threadIdx.x; i < cnt; i += stride) {
            d[i] = f ? ((const u16*)s)[i] : f2b(((const float*)s)[i]);
        }
    }
}

// big[b][n][0:128]=cos*mask, [128:256]=sin*mask  (node-major, kk-contiguous)
__global__ __launch_bounds__(256) void bases_nk_kernel(
    const u16* __restrict__ nodes, const u16* __restrict__ modes,
    const u16* __restrict__ mask, u16* __restrict__ big) {
    int t = threadIdx.x;
    int nl = t >> 2, kp = t & 3;
    int n = blockIdx.x * 64 + nl, b = blockIdx.y;
    float nx = b2f(nodes[((size_t)(b * Nn + n)) * 2]);
    float ny = b2f(nodes[((size_t)(b * Nn + n)) * 2 + 1]);
    float mk = b2f(mask[b * Nn + n]);
    u16 cb[32] __attribute__((aligned(16)));
    u16 sb[32] __attribute__((aligned(16)));
    #pragma unroll
    for (int j = 0; j < 32; j++) {
        int k = kp * 32 + j;
        float m0 = b2f(modes[k * 2]), m1 = b2f(modes[k * 2 + 1]);
        float tt = nx * m0 + ny * m1;
        float s, c;
        sincosf(tt, &s, &c);
        cb[j] = f2b(c * mk);
        sb[j] = f2b(s * mk);
    }
    u16* row = big + ((size_t)b * Nn + n) * BIGW;
    #pragma unroll
    for (int i = 0; i < 4; i++) {
        *(uint4*)(row + kp * 32 + i * 8)       = *(const uint4*)(cb + i * 8);
        *(uint4*)(row + 128 + kp * 32 + i * 8) = *(const uint4*)(sb + i * 8);
    }
}

// h into big[b][n][256:384]; hw_cn[b][c][n] = h*wn
__global__ __launch_bounds__(256) void fc0_nk_kernel(
    const u16* __restrict__ x, const u16* __restrict__ fc0_w,
    const u16* __restrict__ fc0_b, const u16* __restrict__ wn,
    u16* __restrict__ big, u16* __restrict__ hw_cn) {
    int t = threadIdx.x;
    int nl = t >> 2, cp = t & 3;
    int n = blockIdx.x * 64 + nl, b = blockIdx.y;
    const u16* xp = x + ((size_t)(b * Nn + n)) * 3;
    float x0v = b2f(xp[0]), x1v = b2f(xp[1]), x2v = b2f(xp[2]);
    float wv = b2f(wn[b * Nn + n]);
    u16 hb[32] __attribute__((aligned(16)));
    #pragma unroll
    for (int j = 0; j < 32; j++) {
        int c = cp * 32 + j;
        float acc = b2f(fc0_b[c]);
        acc += x0v * b2f(fc0_w[0 * Cc + c]);
        acc += x1v * b2f(fc0_w[1 * Cc + c]);
        acc += x2v * b2f(fc0_w[2 * Cc + c]);
        hb[j] = f2b(acc);
        hw_cn[((size_t)(b * Cc + c)) * Nn + n] = f2b(acc * wv);
    }
    u16* row = big + ((size_t)b * Nn + n) * BIGW + 256 + cp * 32;
    #pragma unroll
    for (int i = 0; i < 4; i++) *(uint4*)(row + i * 8) = *(const uint4*)(hb + i * 8);
}

// one-time: wcT/wsT[l][k][o][i] bf16 from raw [l][i][o][k]; w0T[l][o][i] from w0n [l][i][o]
__global__ __launch_bounds__(256) void transpose_w(
    const void* __restrict__ wcraw, const void* __restrict__ wsraw,
    const u16* __restrict__ w0n,
    u16* __restrict__ wcT, u16* __restrict__ wsT, u16* __restrict__ w0T,
    const int* __restrict__ flag) {
    __shared__ u16 tile[128][136];
    int o = blockIdx.x, l = blockIdx.y, t = threadIdx.x;
    const int f = *flag;
    if (o == 128) {
        int i = t >> 1, oh = (t & 1) * 64;
        #pragma unroll
        for (int j = 0; j < 64; j += 8)
            *(uint4*)&tile[i][oh + j] = *(const uint4*)(w0n + ((size_t)(l * 128 + i)) * 128 + oh + j);
        __syncthreads();
        int o2 = t >> 1, ih = (t & 1) * 64;
        u16 buf[64] __attribute__((aligned(16)));
        #pragma unroll
        for (int j = 0; j < 64; j++) buf[j] = tile[ih + j][o2];
        #pragma unroll
        for (int j = 0; j < 64; j += 8)
            *(uint4*)(w0T + ((size_t)(l * 128 + o2)) * 128 + ih + j) = *(const uint4*)(buf + j);
        return;
    }
    for (int wsel = 0; wsel < 2; wsel++) {
        if (wsel) __syncthreads();
        const void* raw = wsel ? wsraw : wcraw;
        u16* dst = wsel ? wsT : wcT;
        int i = t >> 1, kh = (t & 1) * 64;
        size_t base = (((size_t)(l * 128 + i)) * 128 + o) * 128 + kh;
        if (f) {
            #pragma unroll
            for (int j = 0; j < 64; j += 8)
                *(uint4*)&tile[i][kh + j] = *(const uint4*)((const u16*)raw + base + j);
        } else {
            #pragma unroll
            for (int j = 0; j < 64; j += 4) {
                float4 v = *(const float4*)((const float*)raw + base + j);
                u16 o4[4] __attribute__((aligned(8))) = { f2b(v.x), f2b(v.y), f2b(v.z), f2b(v.w) };
                *(unsigned long long*)&tile[i][kh + j] = *(const unsigned long long*)o4;
            }
        }
        __syncthreads();
        int k = t >> 1, ih = (t & 1) * 64;
        u16 buf[64] __attribute__((aligned(16)));
        #pragma unroll
        for (int j = 0; j < 64; j++) buf[j] = tile[ih + j][k];
        #pragma unroll
        for (int j = 0; j < 64; j += 8)
            *(uint4*)(dst + (((size_t)(l * 128 + k)) * 128 + o) * 128 + ih + j) = *(const uint4*)(buf + j);
    }
}

// x0[b,c] = sum_n hw[b,c,n]*mask[b,n]  (f32 + bf16 copies)
__global__ __launch_bounds__(256) void x0_kernel(
    const u16* __restrict__ hw, const u16* __restrict__ mask,
    float* __restrict__ x0, u16* __restrict__ x0b) {
    int c = blockIdx.x, b = blockIdx.y;
    const u16* row = hw + ((size_t)(b * Cc + c)) * Nn;
    const u16* mrow = mask + (size_t)b * Nn;
    float acc = 0.f;
    for (int n = threadIdx.x; n < Nn; n += 256) acc += b2f(row[n]) * b2f(mrow[n]);
    __shared__ float red[4];
    for (int off = 32; off; off >>= 1) acc += __shfl_down(acc, off, 64);
    if ((threadIdx.x & 63) == 0) red[threadIdx.x >> 6] = acc;
    __syncthreads();
    if (threadIdx.x == 0) {
        float v = red[0] + red[1] + red[2] + red[3];
        x0[b * Cc + c] = v;
        x0b[b * Cc + c] = f2b(v);
    }
}

// MFMA projection, on-the-fly bases; writes pxc/pps in [b][s][k][c] layout
__global__ __launch_bounds__(256) void proj_mfma(
    const u16* __restrict__ hw, const u16* __restrict__ nodes,
    const u16* __restrict__ modes, const u16* __restrict__ mask,
    float* __restrict__ pxc, float* __restrict__ pps) {
    int s = blockIdx.x, kh = blockIdx.y, b = blockIdx.z;
    int w = threadIdx.x >> 6, lane = threadIdx.x & 63;
    int lo = lane & 15, q = lane >> 4;
    int n0 = s * 512;
    int kmode = kh * 64 + w * 16 + lo;
    float m0 = b2f(modes[kmode * 2]), m1 = b2f(modes[kmode * 2 + 1]);
    const u16* ap[8];
    #pragma unroll
    for (int ct = 0; ct < 8; ct++)
        ap[ct] = hw + ((size_t)(b * Cc) + ct * 16 + lo) * Nn + n0 + q * 8;
    const u16* np = nodes + ((size_t)(b * Nn) + n0 + q * 8) * 2;
    const u16* mp = mask + (size_t)b * Nn + n0 + q * 8;
    f4 aC[8] = {}, aS[8] = {};
    for (int js = 0; js < 16; js++) {
        int off = js * 32;
        uint4 nq0 = *(const uint4*)(np + off * 2);
        uint4 nq1 = *(const uint4*)(np + off * 2 + 8);
        uint4 mq  = *(const uint4*)(mp + off);
        float xs[8], ys[8], mk[8];
        xs[0] = b2f(nq0.x & 0xffffu); ys[0] = b2f(nq0.x >> 16);
        xs[1] = b2f(nq0.y & 0xffffu); ys[1] = b2f(nq0.y >> 16);
        xs[2] = b2f(nq0.z & 0xffffu); ys[2] = b2f(nq0.z >> 16);
        xs[3] = b2f(nq0.w & 0xffffu); ys[3] = b2f(nq0.w >> 16);
        xs[4] = b2f(nq1.x & 0xffffu); ys[4] = b2f(nq1.x >> 16);
        xs[5] = b2f(nq1.y & 0xffffu); ys[5] = b2f(nq1.y >> 16);
        xs[6] = b2f(nq1.z & 0xffffu); ys[6] = b2f(nq1.z >> 16);
        xs[7] = b2f(nq1.w & 0xffffu); ys[7] = b2f(nq1.w >> 16);
        mk[0] = b2f(mq.x & 0xffffu);  mk[1] = b2f(mq.x >> 16);
        mk[2] = b2f(mq.y & 0xffffu);  mk[3] = b2f(mq.y >> 16);
        mk[4] = b2f(mq.z & 0xffffu);  mk[5] = b2f(mq.z >> 16);
        mk[6] = b2f(mq.w & 0xffffu);  mk[7] = b2f(mq.w >> 16);
        u16 cf[8] __attribute__((aligned(16)));
        u16 sf[8] __attribute__((aligned(16)));
        #pragma unroll
        for (int j = 0; j < 8; j++) {
            float tt = xs[j] * m0 + ys[j] * m1;
            float sv_, cv_;
            sincosf(tt, &sv_, &cv_);
            cf[j] = f2b(cv_ * mk[j]);
            sf[j] = f2b(sv_ * mk[j]);
        }
        bf8 cv = *(const bf8*)cf;
        bf8 sv = *(const bf8*)sf;
        #pragma unroll
        for (int ct = 0; ct < 8; ct++) {
            bf8 av = *(const bf8*)(ap[ct] + off);
            aC[ct] = __builtin_amdgcn_mfma_f32_16x16x32_bf16(av, cv, aC[ct], 0, 0, 0);
            aS[ct] = __builtin_amdgcn_mfma_f32_16x16x32_bf16(av, sv, aS[ct], 0, 0, 0);
        }
    }
    size_t base = ((size_t)(b * SPLIT + s)) * 16384 + (size_t)kmode * 128;
    #pragma unroll
    for (int ct = 0; ct < 8; ct++) {
        *(f4*)&pxc[base + ct * 16 + q * 4] = aC[ct];
        *(f4*)&pps[base + ct * 16 + q * 4] = aS[ct];
    }
}

// sum partials over s; output bf16 xcT/psT [b][k][c]
__global__ __launch_bounds__(256) void reduce_kernel(
    const float* __restrict__ pxc, const float* __restrict__ pps,
    u16* __restrict__ xcT, u16* __restrict__ psT) {
    int g = blockIdx.x * 256 + threadIdx.x;
    int b = g >> 14, r = g & 16383;
    const float* p1 = pxc + ((size_t)b * SPLIT) * 16384 + r;
    const float* p2 = pps + ((size_t)b * SPLIT) * 16384 + r;
    float a1 = 0.f, a2 = 0.f;
    #pragma unroll
    for (int s2 = 0; s2 < SPLIT; s2++) {
        a1 += p1[(size_t)s2 * 16384];
        a2 += p2[(size_t)s2 * 16384];
    }
    xcT[g] = f2b(a1); psT[g] = f2b(a2);
}

// MFMA mix: per mode k, U[16][i]=[xc(b);ps(b)], D=U·wc / U·ws -> Ablk (+f0 block kb==128)
__global__ __launch_bounds__(256) void mix_mfma(
    const u16* __restrict__ xcT, const u16* __restrict__ psT,
    const u16* __restrict__ wcT, const u16* __restrict__ wsT,
    const u16* __restrict__ w0T, const u16* __restrict__ x0b,
    u16* __restrict__ Ablk, float* __restrict__ f0p, int l) {
    int kb = blockIdx.x;
    int w = threadIdx.x >> 6, lane = threadIdx.x & 63;
    int lo = lane & 15, q = lane >> 4;
    if (kb == 128) {
        const u16* Arow = x0b + (lo & 7) * 128 + q * 8;
        f4 acc[2] = {};
        #pragma unroll
        for (int step = 0; step < 4; step++) {
            bf8 av = *(const bf8*)(Arow + step * 32);
            #pragma unroll
            for (int nt = 0; nt < 2; nt++) {
                int o = w * 32 + nt * 16 + lo;
                bf8 bv = *(const bf8*)(w0T + ((size_t)(l * 128 + o)) * 128 + q * 8 + step * 32);
                acc[nt] = __builtin_amdgcn_mfma_f32_16x16x32_bf16(av, bv, acc[nt], 0, 0, 0);
            }
        }
        if (q < 2) {
            #pragma unroll
            for (int nt = 0; nt < 2; nt++)
                #pragma unroll
                for (int r = 0; r < 4; r++) {
                    int bb = q * 4 + r, o = w * 32 + nt * 16 + lo;
                    f0p[bb * 128 + o] = acc[nt][r];
                }
        }
        return;
    }
    int k = kb;
    const u16* Arow = (lo < 8)
        ? xcT + ((size_t)(lo * 128 + k)) * 128 + q * 8
        : psT + ((size_t)((lo - 8) * 128 + k)) * 128 + q * 8;
    const u16* wc_l = wcT + ((size_t)(l * 128 + k)) * (128 * 128);
    const u16* ws_l = wsT + ((size_t)(l * 128 + k)) * (128 * 128);
    f4 accC[2] = {}, accS[2] = {};
    #pragma unroll
    for (int step = 0; step < 4; step++) {
        bf8 av = *(const bf8*)(Arow + step * 32);
        #pragma unroll
        for (int nt = 0; nt < 2; nt++) {
            int o = w * 32 + nt * 16 + lo;
            bf8 bc = *(const bf8*)(wc_l + (size_t)o * 128 + q * 8 + step * 32);
            bf8 bs = *(const bf8*)(ws_l + (size_t)o * 128 + q * 8 + step * 32);
            accC[nt] = __builtin_amdgcn_mfma_f32_16x16x32_bf16(av, bc, accC[nt], 0, 0, 0);
            accS[nt] = __builtin_amdgcn_mfma_f32_16x16x32_bf16(av, bs, accS[nt], 0, 0, 0);
        }
    }
    #pragma unroll
    for (int nt = 0; nt < 2; nt++)
        #pragma unroll
        for (int r = 0; r < 4; r++) {
            float uc = accC[nt][r], us = accS[nt][r];
            float ucp = __shfl_xor(uc, 32, 64);
            float usp = __shfl_xor(us, 32, 64);
            if (q < 2) {
                int bb = q * 4 + r, o = w * 32 + nt * 16 + lo;
                float fcv = uc + usp;     // xc.wc + ps.ws
                float fsv = us - ucp;     // xc.ws - ps.wc
                Ablk[(((size_t)(bb * 12 + (k >> 5))) * 128 + o) * 32 + (k & 31)] = f2b(2.f * fcv);
                Ablk[(((size_t)(bb * 12 + 4 + (k >> 5))) * 128 + o) * 32 + (k & 31)] = f2b(-2.f * fsv);
            }
        }
}

// fill Ablk conv segment (ks 8..11) from conv_w[l]
__global__ __launch_bounds__(256) void conv_fill(
    const u16* __restrict__ conv_w, u16* __restrict__ Ablk, int l) {
    int ks2 = blockIdx.x, b = blockIdx.y, t = threadIdx.x;
    int o = t >> 1, half = t & 1;
    const u16* src = conv_w + ((size_t)(l * 128 + o)) * 128 + ks2 * 32 + half * 16;
    u16* dst = Ablk + (((size_t)(b * 12 + 8 + ks2)) * 128 + o) * 32 + half * 16;
    *(uint4*)dst = *(const uint4*)src;
    *(uint4*)(dst + 8) = *(const uint4*)(src + 8);
}

// Ablk1[ks(4)][o(128)][32] = fc1_w^T
__global__ __launch_bounds__(256) void buildA1_blk(
    const u16* __restrict__ fc1_w, u16* __restrict__ Ablk1) {
    int ks = blockIdx.x, t = threadIdx.x;
    int o = t >> 1, half = t & 1;
    u16 ov[16] __attribute__((aligned(16)));
    #pragma unroll
    for (int j = 0; j < 16; j++) {
        int kk = ks * 32 + half * 16 + j;
        ov[j] = fc1_w[kk * 128 + o];
    }
    u16* dst = Ablk1 + ((size_t)ks * 128 + o) * 32 + half * 16;
    *(uint4*)dst = *(const uint4*)ov;
    *(uint4*)(dst + 8) = *(const uint4*)(ov + 8);
}

// MFMA combine: block 128o x 128n, wave 128o x 32n.
// EPI 0: +f0*mask+bias, gelu, write big.h + hw_cn(=h*wn). EPI 1: same no gelu, big only.
// EPI 2: +bias, gelu, fused fc2 -> final out
template <int EPI, int NKS, int KKOFF>
__global__ __launch_bounds__(256) void combine_mfma(
    const u16* __restrict__ Ablk, long astr, u16* __restrict__ big,
    const float* __restrict__ f0p, const u16* __restrict__ bias,
    const u16* __restrict__ mask, const u16* __restrict__ wn,
    u16* __restrict__ hw_cn,
    const u16* __restrict__ fc2w, const u16* __restrict__ fc2b,
    void* __restrict__ out, const int* __restrict__ flag) {
    __shared__ u16 tr[4][16][136];
    int b = blockIdx.y;
    int w = threadIdx.x >> 6, lane = threadIdx.x & 63;
    int lo = lane & 15, q = lane >> 4;
    int nbw = blockIdx.x * 128 + w * 32;
    const u16* Ap = Ablk + (size_t)b * astr + (size_t)lo * 32 + q * 8;
    const u16* Bp[2];
    #pragma unroll
    for (int nt = 0; nt < 2; nt++)
        Bp[nt] = big + ((size_t)b * Nn + nbw + nt * 16 + lo) * BIGW + KKOFF + q * 8;
    f4 acc[8][2] = {};
    #pragma unroll
    for (int ks = 0; ks < NKS; ks++) {
        bf8 av[8], bv[2];
        #pragma unroll
        for (int ot = 0; ot < 8; ot++) av[ot] = *(const bf8*)(Ap + ks * 4096 + ot * 512);
        #pragma unroll
        for (int nt = 0; nt < 2; nt++) bv[nt] = *(const bf8*)(Bp[nt] + ks * 32);
        #pragma unroll
        for (int ot = 0; ot < 8; ot++)
            #pragma unroll
            for (int nt = 0; nt < 2; nt++)
                acc[ot][nt] = __builtin_amdgcn_mfma_f32_16x16x32_bf16(av[ot], bv[nt], acc[ot][nt], 0, 0, 0);
    }

    if (EPI == 2) {
        const int f_bf16 = *flag;
        float bv2 = b2f(fc2b[0]);
        #pragma unroll
        for (int nt = 0; nt < 2; nt++) {
            int n = nbw + nt * 16 + lo;
            float s = 0.f;
            #pragma unroll
            for (int ot = 0; ot < 8; ot++)
                #pragma unroll
                for (int r = 0; r < 4; r++) {
                    int o = ot * 16 + q * 4 + r;
                    float v = acc[ot][nt][r] + b2f(bias[o]);
                    v = gelu_f(v);
                    s += b2f(fc2w[o]) * v;
                }
            s += __shfl_xor(s, 16, 64);
            s += __shfl_xor(s, 32, 64);
            s = (s + bv2) * b2f(mask[(size_t)b * Nn + n]);
            if (q == 0) {
                size_t off = (size_t)b * Nn + n;
                if (f_bf16) ((u16*)out)[off] = f2b(s);
                else        ((float*)out)[off] = s;
            }
        }
    } else {
        #pragma unroll
        for (int nt = 0; nt < 2; nt++) {
            int n = nbw + nt * 16 + lo;
            float mv = b2f(mask[(size_t)b * Nn + n]);
            __syncthreads();
            #pragma unroll
            for (int ot = 0; ot < 8; ot++) {
                u16 hv[4] __attribute__((aligned(8)));
                #pragma unroll
                for (int r = 0; r < 4; r++) {
                    int o = ot * 16 + q * 4 + r;
                    float v = acc[ot][nt][r] + b2f(bias[o]) + f0p[b * Cc + o] * mv;
                    if (EPI == 0) v = gelu_f(v);
                    hv[r] = f2b(v);
                }
                *(uint2*)&tr[w][lo][ot * 16 + q * 4] = *(const uint2*)hv;
            }
            __syncthreads();
            #pragma unroll
            for (int i = 0; i < 4; i++) {
                int id = i * 64 + lane;
                int nl2 = id >> 4, ch = id & 15;
                uint4 v4 = *(const uint4*)&tr[w][nl2][ch * 8];
                *(uint4*)&big[((size_t)b * Nn + nbw + nt * 16 + nl2) * BIGW + 256 + ch * 8] = v4;
            }
            if (EPI == 0) {
                // emit hw_cn[c][n] from the same tr tile
                float wnv[16];
                #pragma unroll
                for (int j = 0; j < 16; j++)
                    wnv[j] = b2f(wn[(size_t)b * Nn + nbw + nt * 16 + j]);
                #pragma unroll
                for (int cc = 0; cc < 2; cc++) {
                    int c = lane * 2 + cc;
                    u16 hvv[16] __attribute__((aligned(16)));
                    #pragma unroll
                    for (int j = 0; j < 16; j++) hvv[j] = f2b(b2f(tr[w][j][c]) * wnv[j]);
                    u16* dstp = hw_cn + ((size_t)(b * Cc + c)) * Nn + nbw + nt * 16;
                    *(uint4*)dstp = *(const uint4*)hvv;
                    *(uint4*)(dstp + 8) = *(const uint4*)(hvv + 8);
                }
            }
        }
    }
}

extern "C" void kernel_launch(void* const* d_in, const int* in_sizes, int n_in,
                              void* d_out, int out_size, void* d_ws, size_t ws_size,
                              hipStream_t stream) {
    char* p = (char*)d_ws;
    auto alloc = [&](size_t bytes) { void* r = (void*)p; p += (bytes + 255) & ~(size_t)255; return r; };

    int* flag = (int*)alloc(256);

    // normalized bf16 copies of inputs EXCEPT wc(7)/ws_(8) (read raw, transposed below)
    SegTable tab;
    u16* nin[16];
    for (int i = 0; i < 16; i++) {
        tab.src[i] = d_in[i];
        if (i == 7 || i == 8) {
            nin[i] = (u16*)flag;
            tab.dst[i] = nin[i];
            tab.count[i] = 0;
        } else {
            int cnt = in_sizes[i];
            nin[i] = (u16*)alloc((size_t)cnt * 2);
            tab.dst[i] = nin[i];
            tab.count[i] = cnt;
        }
    }
    const u16* x      = nin[0];
    const u16* nodes  = nin[1];
    const u16* mask   = nin[2];
    const u16* wn     = nin[3];
    const u16* modes  = nin[4];
    const u16* fc0_w  = nin[5];
    const u16* fc0_b  = nin[6];
    const u16* w0n    = nin[9];
    const u16* conv_w = nin[10];
    const u16* conv_b = nin[11];
    const u16* fc1_w  = nin[12];
    const u16* fc1_b  = nin[13];
    const u16* fc2_w  = nin[14];
    const u16* fc2_b  = nin[15];

    u16* big    = (u16*)alloc((size_t)Bb * Nn * BIGW * 2);           // 100.7 MB
    u16* hw_cn  = (u16*)alloc((size_t)Bb * Cc * Nn * 2);             // 33.6 MB
    float* pxc  = (float*)alloc((size_t)Bb * SPLIT * Cc * Kk * 4);   // 16.8 MB
    float* pps  = (float*)alloc((size_t)Bb * SPLIT * Cc * Kk * 4);   // 16.8 MB
    u16* wcT    = (u16*)alloc((size_t)Ll * Kk * Cc * Cc * 2);        // 16.8 MB
    u16* wsT    = (u16*)alloc((size_t)Ll * Kk * Cc * Cc * 2);        // 16.8 MB
    u16* w0T    = (u16*)alloc((size_t)Ll * Cc * Cc * 2);
    u16* xcT    = (u16*)alloc((size_t)Bb * Kk * Cc * 2);
    u16* psT    = (u16*)alloc((size_t)Bb * Kk * Cc * 2);
    float* x0f  = (float*)alloc((size_t)Bb * Cc * 4);
    u16* x0b    = (u16*)alloc((size_t)Bb * Cc * 2);
    float* f0f  = (float*)alloc((size_t)Bb * Cc * 4);
    u16* Ablk   = (u16*)alloc((size_t)Bb * 12 * 128 * 32 * 2);
    u16* Ablk1  = (u16*)alloc((size_t)4 * 128 * 32 * 2);
    // total ws ~= 205 MB (< 207 MB proven safe)

    const long ASTR = 12L * 128 * 32;

    detect_kernel<<<1, 64, 0, stream>>>((const unsigned int*)d_in[2], flag);
    convert_kernel<<<512, 256, 0, stream>>>(tab, flag);

    transpose_w<<<dim3(129, Ll), 256, 0, stream>>>(d_in[7], d_in[8], w0n, wcT, wsT, w0T, flag);
    bases_nk_kernel<<<dim3(Nn / 64, Bb), 256, 0, stream>>>(nodes, modes, mask, big);
    fc0_nk_kernel<<<dim3(Nn / 64, Bb), 256, 0, stream>>>(x, fc0_w, fc0_b, wn, big, hw_cn);

    for (int l = 0; l < Ll; l++) {
        x0_kernel<<<dim3(Cc, Bb), 256, 0, stream>>>(hw_cn, mask, x0f, x0b);
        proj_mfma<<<dim3(SPLIT, 2, Bb), 256, 0, stream>>>(hw_cn, nodes, modes, mask, pxc, pps);
        reduce_kernel<<<dim3((Bb * Cc * Kk) / 256), 256, 0, stream>>>(pxc, pps, xcT, psT);
        conv_fill<<<dim3(4, Bb), 256, 0, stream>>>(conv_w, Ablk, l);
        mix_mfma<<<dim3(129), 256, 0, stream>>>(xcT, psT, wcT, wsT, w0T, x0b, Ablk, f0f, l);
        if (l < Ll - 1) {
            combine_mfma<0, 12, 0><<<dim3(Nn / 128, Bb), 256, 0, stream>>>(
                Ablk, ASTR, big, f0f, conv_b + l * Cc, mask, wn, hw_cn, fc2_w, fc2_b, d_out, flag);
        } else {
            combine_mfma<1, 12, 0><<<dim3(Nn / 128, Bb), 256, 0, stream>>>(
                Ablk, ASTR, big, f0f, conv_b + l * Cc, mask, wn, hw_cn, fc2_w, fc2_b, d_out, flag);
        }
    }

    buildA1_blk<<<dim3(4), 256, 0, stream>>>(fc1_w, Ablk1);
    combine_mfma<2, 4, 256><<<dim3(Nn / 128, Bb), 256, 0, stream>>>(
        Ablk1, 0L, big, f0f, fc1_b, mask, wn, hw_cn, fc2_w, fc2_b, d_out, flag);
}

// Round 7
// 813.736 us; speedup vs baseline: 2.3623x; 1.1114x over previous
//
#include <hip/hip_runtime.h>

using u16 = unsigned short;
typedef short bf8 __attribute__((ext_vector_type(8)));
typedef float f4 __attribute__((ext_vector_type(4)));

constexpr int Bb = 8;
constexpr int Nn = 16384;
constexpr int Kk = 128;
constexpr int Cc = 128;
constexpr int Ll = 4;
constexpr int SPLIT = 32;

__device__ __forceinline__ float b2f(u16 u) {
    union { unsigned int i; float f; } v; v.i = ((unsigned int)u) << 16; return v.f;
}
__device__ __forceinline__ u16 f2b(float f) {
    union { float f; unsigned int i; } v; v.f = f;
    unsigned int i = v.i;
    return (u16)((i + 0x7fffu + ((i >> 16) & 1u)) >> 16);
}
__device__ __forceinline__ float gelu_f(float x) {
    return 0.5f * x * (1.0f + erff(x * 0.70710678118654752f));
}

// ---- dtype detection + input normalization ----
__global__ void detect_kernel(const unsigned int* __restrict__ maskw, int* __restrict__ flag) {
    if (threadIdx.x == 0 && blockIdx.x == 0)
        *flag = ((maskw[0] & 0xFFFFu) != 0u) ? 1 : 0;   // 1 = inputs are bf16
}

struct SegTable {
    const void* src[16];
    u16* dst[16];
    int count[16];
};

__global__ __launch_bounds__(256) void convert_kernel(SegTable t, const int* __restrict__ flag) {
    const int f = *flag;
    const int stride = gridDim.x * 256;
    for (int seg = 0; seg < 16; ++seg) {
        const int cnt = t.count[seg];
        const void* s = t.src[seg];
        u16* d = t.dst[seg];
        for (int i = blockIdx.x * 256 + threadIdx.x; i < cnt; i += stride) {
            d[i] = f ? ((const u16*)s)[i] : f2b(((const float*)s)[i]);
        }
    }
}

// bigB[b][n][0:128]=cos*mask, [128:256]=sin*mask
__global__ __launch_bounds__(256) void bases_nk_kernel(
    const u16* __restrict__ nodes, const u16* __restrict__ modes,
    const u16* __restrict__ mask, u16* __restrict__ bigB) {
    int t = threadIdx.x;
    int nl = t >> 2, kp = t & 3;
    int n = blockIdx.x * 64 + nl, b = blockIdx.y;
    float nx = b2f(nodes[((size_t)(b * Nn + n)) * 2]);
    float ny = b2f(nodes[((size_t)(b * Nn + n)) * 2 + 1]);
    float mk = b2f(mask[b * Nn + n]);
    u16 cb[32] __attribute__((aligned(16)));
    u16 sb[32] __attribute__((aligned(16)));
    #pragma unroll
    for (int j = 0; j < 32; j++) {
        int k = kp * 32 + j;
        float m0 = b2f(modes[k * 2]), m1 = b2f(modes[k * 2 + 1]);
        float tt = nx * m0 + ny * m1;
        cb[j] = f2b(__cosf(tt) * mk);
        sb[j] = f2b(__sinf(tt) * mk);
    }
    u16* row = bigB + ((size_t)b * Nn + n) * 256;
    #pragma unroll
    for (int i = 0; i < 4; i++) {
        *(uint4*)(row + kp * 32 + i * 8)       = *(const uint4*)(cb + i * 8);
        *(uint4*)(row + 128 + kp * 32 + i * 8) = *(const uint4*)(sb + i * 8);
    }
}

// h into hA[b][n][128]; hw_cn[b][c][n] = h*wn
__global__ __launch_bounds__(256) void fc0_nk_kernel(
    const u16* __restrict__ x, const u16* __restrict__ fc0_w,
    const u16* __restrict__ fc0_b, const u16* __restrict__ wn,
    u16* __restrict__ hA, u16* __restrict__ hw_cn) {
    int t = threadIdx.x;
    int nl = t >> 2, cp = t & 3;
    int n = blockIdx.x * 64 + nl, b = blockIdx.y;
    const u16* xp = x + ((size_t)(b * Nn + n)) * 3;
    float x0v = b2f(xp[0]), x1v = b2f(xp[1]), x2v = b2f(xp[2]);
    float wv = b2f(wn[b * Nn + n]);
    u16 hb[32] __attribute__((aligned(16)));
    #pragma unroll
    for (int j = 0; j < 32; j++) {
        int c = cp * 32 + j;
        float acc = b2f(fc0_b[c]);
        acc += x0v * b2f(fc0_w[0 * Cc + c]);
        acc += x1v * b2f(fc0_w[1 * Cc + c]);
        acc += x2v * b2f(fc0_w[2 * Cc + c]);
        hb[j] = f2b(acc);
        hw_cn[((size_t)(b * Cc + c)) * Nn + n] = f2b(acc * wv);
    }
    u16* row = hA + ((size_t)b * Nn + n) * 128 + cp * 32;
    #pragma unroll
    for (int i = 0; i < 4; i++) *(uint4*)(row + i * 8) = *(const uint4*)(hb + i * 8);
}

// per-layer: wcTl/wsTl[k][o][i] bf16 from raw [l][i][o][k]; w0T[o][i]
__global__ __launch_bounds__(256) void transpose_w_layer(
    const void* __restrict__ wcraw, const void* __restrict__ wsraw,
    const u16* __restrict__ w0n,
    u16* __restrict__ wcTl, u16* __restrict__ wsTl, u16* __restrict__ w0T,
    const int* __restrict__ flag, int l) {
    __shared__ u16 tile[128][136];
    int o = blockIdx.x, t = threadIdx.x;
    const int f = *flag;
    if (o == 128) {
        int i = t >> 1, oh = (t & 1) * 64;
        #pragma unroll
        for (int j = 0; j < 64; j += 8)
            *(uint4*)&tile[i][oh + j] = *(const uint4*)(w0n + ((size_t)(l * 128 + i)) * 128 + oh + j);
        __syncthreads();
        int o2 = t >> 1, ih = (t & 1) * 64;
        u16 buf[64] __attribute__((aligned(16)));
        #pragma unroll
        for (int j = 0; j < 64; j++) buf[j] = tile[ih + j][o2];
        #pragma unroll
        for (int j = 0; j < 64; j += 8)
            *(uint4*)(w0T + (size_t)o2 * 128 + ih + j) = *(const uint4*)(buf + j);
        return;
    }
    for (int wsel = 0; wsel < 2; wsel++) {
        if (wsel) __syncthreads();
        const void* raw = wsel ? wsraw : wcraw;
        u16* dst = wsel ? wsTl : wcTl;
        int i = t >> 1, kh = (t & 1) * 64;
        size_t base = (((size_t)(l * 128 + i)) * 128 + o) * 128 + kh;
        if (f) {
            #pragma unroll
            for (int j = 0; j < 64; j += 8)
                *(uint4*)&tile[i][kh + j] = *(const uint4*)((const u16*)raw + base + j);
        } else {
            #pragma unroll
            for (int j = 0; j < 64; j += 4) {
                float4 v = *(const float4*)((const float*)raw + base + j);
                u16 o4[4] __attribute__((aligned(8))) = { f2b(v.x), f2b(v.y), f2b(v.z), f2b(v.w) };
                *(unsigned long long*)&tile[i][kh + j] = *(const unsigned long long*)o4;
            }
        }
        __syncthreads();
        int k = t >> 1, ih = (t & 1) * 64;
        u16 buf[64] __attribute__((aligned(16)));
        #pragma unroll
        for (int j = 0; j < 64; j++) buf[j] = tile[ih + j][k];
        #pragma unroll
        for (int j = 0; j < 64; j += 8)
            *(uint4*)(dst + ((size_t)k * 128 + o) * 128 + ih + j) = *(const uint4*)(buf + j);
    }
}

// x0[b,c] = sum_n hw[b,c,n]*mask[b,n]
__global__ __launch_bounds__(256) void x0_kernel(
    const u16* __restrict__ hw, const u16* __restrict__ mask,
    float* __restrict__ x0, u16* __restrict__ x0b) {
    int c = blockIdx.x, b = blockIdx.y;
    const u16* row = hw + ((size_t)(b * Cc + c)) * Nn;
    const u16* mrow = mask + (size_t)b * Nn;
    float acc = 0.f;
    for (int n = threadIdx.x; n < Nn; n += 256) acc += b2f(row[n]) * b2f(mrow[n]);
    __shared__ float red[4];
    for (int off = 32; off; off >>= 1) acc += __shfl_down(acc, off, 64);
    if ((threadIdx.x & 63) == 0) red[threadIdx.x >> 6] = acc;
    __syncthreads();
    if (threadIdx.x == 0) {
        float v = red[0] + red[1] + red[2] + red[3];
        x0[b * Cc + c] = v;
        x0b[b * Cc + c] = f2b(v);
    }
}

// MFMA projection, fast on-the-fly bases; bf16 partials [b][s][k][c]
__global__ __launch_bounds__(256) void proj_mfma(
    const u16* __restrict__ hw, const u16* __restrict__ nodes,
    const u16* __restrict__ modes, const u16* __restrict__ mask,
    u16* __restrict__ pxc, u16* __restrict__ pps) {
    int s = blockIdx.x, kh = blockIdx.y, b = blockIdx.z;
    int w = threadIdx.x >> 6, lane = threadIdx.x & 63;
    int lo = lane & 15, q = lane >> 4;
    int n0 = s * 512;
    int kmode = kh * 64 + w * 16 + lo;
    float m0 = b2f(modes[kmode * 2]), m1 = b2f(modes[kmode * 2 + 1]);
    const u16* ap[8];
    #pragma unroll
    for (int ct = 0; ct < 8; ct++)
        ap[ct] = hw + ((size_t)(b * Cc) + ct * 16 + lo) * Nn + n0 + q * 8;
    const u16* np = nodes + ((size_t)(b * Nn) + n0 + q * 8) * 2;
    const u16* mp = mask + (size_t)b * Nn + n0 + q * 8;
    f4 aC[8] = {}, aS[8] = {};
    for (int js = 0; js < 16; js++) {
        int off = js * 32;
        uint4 nq0 = *(const uint4*)(np + off * 2);
        uint4 nq1 = *(const uint4*)(np + off * 2 + 8);
        uint4 mq  = *(const uint4*)(mp + off);
        float xs[8], ys[8], mk[8];
        xs[0] = b2f(nq0.x & 0xffffu); ys[0] = b2f(nq0.x >> 16);
        xs[1] = b2f(nq0.y & 0xffffu); ys[1] = b2f(nq0.y >> 16);
        xs[2] = b2f(nq0.z & 0xffffu); ys[2] = b2f(nq0.z >> 16);
        xs[3] = b2f(nq0.w & 0xffffu); ys[3] = b2f(nq0.w >> 16);
        xs[4] = b2f(nq1.x & 0xffffu); ys[4] = b2f(nq1.x >> 16);
        xs[5] = b2f(nq1.y & 0xffffu); ys[5] = b2f(nq1.y >> 16);
        xs[6] = b2f(nq1.z & 0xffffu); ys[6] = b2f(nq1.z >> 16);
        xs[7] = b2f(nq1.w & 0xffffu); ys[7] = b2f(nq1.w >> 16);
        mk[0] = b2f(mq.x & 0xffffu);  mk[1] = b2f(mq.x >> 16);
        mk[2] = b2f(mq.y & 0xffffu);  mk[3] = b2f(mq.y >> 16);
        mk[4] = b2f(mq.z & 0xffffu);  mk[5] = b2f(mq.z >> 16);
        mk[6] = b2f(mq.w & 0xffffu);  mk[7] = b2f(mq.w >> 16);
        u16 cf[8] __attribute__((aligned(16)));
        u16 sf[8] __attribute__((aligned(16)));
        #pragma unroll
        for (int j = 0; j < 8; j++) {
            float tt = xs[j] * m0 + ys[j] * m1;
            cf[j] = f2b(__cosf(tt) * mk[j]);
            sf[j] = f2b(__sinf(tt) * mk[j]);
        }
        bf8 cv = *(const bf8*)cf;
        bf8 sv = *(const bf8*)sf;
        #pragma unroll
        for (int ct = 0; ct < 8; ct++) {
            bf8 av = *(const bf8*)(ap[ct] + off);
            aC[ct] = __builtin_amdgcn_mfma_f32_16x16x32_bf16(av, cv, aC[ct], 0, 0, 0);
            aS[ct] = __builtin_amdgcn_mfma_f32_16x16x32_bf16(av, sv, aS[ct], 0, 0, 0);
        }
    }
    size_t base = ((size_t)(b * SPLIT + s)) * 16384 + (size_t)kmode * 128;
    #pragma unroll
    for (int ct = 0; ct < 8; ct++) {
        u16 pc[4] __attribute__((aligned(8)));
        u16 pssv[4] __attribute__((aligned(8)));
        #pragma unroll
        for (int r = 0; r < 4; r++) { pc[r] = f2b(aC[ct][r]); pssv[r] = f2b(aS[ct][r]); }
        *(uint2*)&pxc[base + ct * 16 + q * 4] = *(const uint2*)pc;
        *(uint2*)&pps[base + ct * 16 + q * 4] = *(const uint2*)pssv;
    }
}

// sum bf16 partials over s -> bf16 xcT/psT [b][k][c]
__global__ __launch_bounds__(256) void reduce_kernel(
    const u16* __restrict__ pxc, const u16* __restrict__ pps,
    u16* __restrict__ xcT, u16* __restrict__ psT) {
    int g = blockIdx.x * 256 + threadIdx.x;
    int b = g >> 14, r = g & 16383;
    const u16* p1 = pxc + ((size_t)b * SPLIT) * 16384 + r;
    const u16* p2 = pps + ((size_t)b * SPLIT) * 16384 + r;
    float a1 = 0.f, a2 = 0.f;
    #pragma unroll
    for (int s2 = 0; s2 < SPLIT; s2++) {
        a1 += b2f(p1[(size_t)s2 * 16384]);
        a2 += b2f(p2[(size_t)s2 * 16384]);
    }
    xcT[g] = f2b(a1); psT[g] = f2b(a2);
}

// MFMA mix: per mode k, U[16][i]=[xc(b);ps(b)], -> Ablk (+f0 block kb==128)
__global__ __launch_bounds__(256) void mix_mfma(
    const u16* __restrict__ xcT, const u16* __restrict__ psT,
    const u16* __restrict__ wcTl, const u16* __restrict__ wsTl,
    const u16* __restrict__ w0T, const u16* __restrict__ x0b,
    u16* __restrict__ Ablk, float* __restrict__ f0p) {
    int kb = blockIdx.x;
    int w = threadIdx.x >> 6, lane = threadIdx.x & 63;
    int lo = lane & 15, q = lane >> 4;
    if (kb == 128) {
        const u16* Arow = x0b + (lo & 7) * 128 + q * 8;
        f4 acc[2] = {};
        #pragma unroll
        for (int step = 0; step < 4; step++) {
            bf8 av = *(const bf8*)(Arow + step * 32);
            #pragma unroll
            for (int nt = 0; nt < 2; nt++) {
                int o = w * 32 + nt * 16 + lo;
                bf8 bv = *(const bf8*)(w0T + (size_t)o * 128 + q * 8 + step * 32);
                acc[nt] = __builtin_amdgcn_mfma_f32_16x16x32_bf16(av, bv, acc[nt], 0, 0, 0);
            }
        }
        if (q < 2) {
            #pragma unroll
            for (int nt = 0; nt < 2; nt++)
                #pragma unroll
                for (int r = 0; r < 4; r++) {
                    int bb = q * 4 + r, o = w * 32 + nt * 16 + lo;
                    f0p[bb * 128 + o] = acc[nt][r];
                }
        }
        return;
    }
    int k = kb;
    const u16* Arow = (lo < 8)
        ? xcT + ((size_t)(lo * 128 + k)) * 128 + q * 8
        : psT + ((size_t)((lo - 8) * 128 + k)) * 128 + q * 8;
    const u16* wc_l = wcTl + (size_t)k * (128 * 128);
    const u16* ws_l = wsTl + (size_t)k * (128 * 128);
    f4 accC[2] = {}, accS[2] = {};
    #pragma unroll
    for (int step = 0; step < 4; step++) {
        bf8 av = *(const bf8*)(Arow + step * 32);
        #pragma unroll
        for (int nt = 0; nt < 2; nt++) {
            int o = w * 32 + nt * 16 + lo;
            bf8 bc = *(const bf8*)(wc_l + (size_t)o * 128 + q * 8 + step * 32);
            bf8 bs = *(const bf8*)(ws_l + (size_t)o * 128 + q * 8 + step * 32);
            accC[nt] = __builtin_amdgcn_mfma_f32_16x16x32_bf16(av, bc, accC[nt], 0, 0, 0);
            accS[nt] = __builtin_amdgcn_mfma_f32_16x16x32_bf16(av, bs, accS[nt], 0, 0, 0);
        }
    }
    #pragma unroll
    for (int nt = 0; nt < 2; nt++)
        #pragma unroll
        for (int r = 0; r < 4; r++) {
            float uc = accC[nt][r], us = accS[nt][r];
            float ucp = __shfl_xor(uc, 32, 64);
            float usp = __shfl_xor(us, 32, 64);
            if (q < 2) {
                int bb = q * 4 + r, o = w * 32 + nt * 16 + lo;
                float fcv = uc + usp;
                float fsv = us - ucp;
                Ablk[(((size_t)(bb * 12 + (k >> 5))) * 128 + o) * 32 + (k & 31)] = f2b(2.f * fcv);
                Ablk[(((size_t)(bb * 12 + 4 + (k >> 5))) * 128 + o) * 32 + (k & 31)] = f2b(-2.f * fsv);
            }
        }
}

// fill Ablk conv segment (ks 8..11)
__global__ __launch_bounds__(256) void conv_fill(
    const u16* __restrict__ conv_w, u16* __restrict__ Ablk, int l) {
    int ks2 = blockIdx.x, b = blockIdx.y, t = threadIdx.x;
    int o = t >> 1, half = t & 1;
    const u16* src = conv_w + ((size_t)(l * 128 + o)) * 128 + ks2 * 32 + half * 16;
    u16* dst = Ablk + (((size_t)(b * 12 + 8 + ks2)) * 128 + o) * 32 + half * 16;
    *(uint4*)dst = *(const uint4*)src;
    *(uint4*)(dst + 8) = *(const uint4*)(src + 8);
}

// Ablk1[ks(4)][o(128)][32] = fc1_w^T
__global__ __launch_bounds__(256) void buildA1_blk(
    const u16* __restrict__ fc1_w, u16* __restrict__ Ablk1) {
    int ks = blockIdx.x, t = threadIdx.x;
    int o = t >> 1, half = t & 1;
    u16 ov[16] __attribute__((aligned(16)));
    #pragma unroll
    for (int j = 0; j < 16; j++) {
        int kk = ks * 32 + half * 16 + j;
        ov[j] = fc1_w[kk * 128 + o];
    }
    u16* dst = Ablk1 + ((size_t)ks * 128 + o) * 32 + half * 16;
    *(uint4*)dst = *(const uint4*)ov;
    *(uint4*)(dst + 8) = *(const uint4*)(ov + 8);
}

// MFMA combine v3: o-split. Block 64o x 128n (oh = blockIdx.y), wave 64o x 32n,
// acc[4][2], double-buffered fragment prefetch. B rows: ks<8 -> bigB (256-wide),
// ks>=8 -> hX (128-wide). EPI2: all from hX.
// EPI 0: gelu, write hY + hw_cn. EPI 1: no gelu, hY only. EPI 2: fc1 gelu + fc2 partial -> psum.
template <int EPI, int NKS>
__global__ __launch_bounds__(256) void combine_mfma(
    const u16* __restrict__ Ablk, long astr,
    const u16* __restrict__ bigB, const u16* __restrict__ hX,
    u16* __restrict__ hY, u16* __restrict__ hw_cn,
    const float* __restrict__ f0p, const u16* __restrict__ bias,
    const u16* __restrict__ mask, const u16* __restrict__ wn,
    const u16* __restrict__ fc2w, float* __restrict__ psum) {
    __shared__ u16 tr2[4][32][72];
    int b = blockIdx.z, oh = blockIdx.y;
    int w = threadIdx.x >> 6, lane = threadIdx.x & 63;
    int lo = lane & 15, q = lane >> 4;
    int nbw = blockIdx.x * 128 + w * 32;
    const u16* Ap = Ablk + (size_t)b * astr + (size_t)(oh * 64 + lo) * 32 + q * 8;
    const u16* Bbp[2];
    const u16* Bhp[2];
    #pragma unroll
    for (int nt = 0; nt < 2; nt++) {
        size_t row = (size_t)b * Nn + nbw + nt * 16 + lo;
        Bbp[nt] = bigB + row * 256 + q * 8;
        Bhp[nt] = hX + row * 128 + q * 8;
    }
    auto loadA = [&](int ks, bf8* av) {
        #pragma unroll
        for (int ot = 0; ot < 4; ot++)
            av[ot] = *(const bf8*)(Ap + (size_t)ks * 4096 + ot * 512);
    };
    auto loadB = [&](int ks, bf8* bv) {
        #pragma unroll
        for (int nt = 0; nt < 2; nt++) {
            if (EPI == 2) bv[nt] = *(const bf8*)(Bhp[nt] + ks * 32);
            else bv[nt] = (ks < 8) ? *(const bf8*)(Bbp[nt] + ks * 32)
                                   : *(const bf8*)(Bhp[nt] + (ks - 8) * 32);
        }
    };
    f4 acc[4][2] = {};
    bf8 av0[4], bv0[2], av1[4], bv1[2];
    loadA(0, av0); loadB(0, bv0);
    #pragma unroll
    for (int ks = 0; ks < NKS; ks++) {
        bf8* avc = (ks & 1) ? av1 : av0;
        bf8* bvc = (ks & 1) ? bv1 : bv0;
        bf8* avn = (ks & 1) ? av0 : av1;
        bf8* bvn = (ks & 1) ? bv0 : bv1;
        if (ks + 1 < NKS) { loadA(ks + 1, avn); loadB(ks + 1, bvn); }
        #pragma unroll
        for (int ot = 0; ot < 4; ot++)
            #pragma unroll
            for (int nt = 0; nt < 2; nt++)
                acc[ot][nt] = __builtin_amdgcn_mfma_f32_16x16x32_bf16(avc[ot], bvc[nt], acc[ot][nt], 0, 0, 0);
    }

    if (EPI == 2) {
        #pragma unroll
        for (int nt = 0; nt < 2; nt++) {
            int n = nbw + nt * 16 + lo;
            float s = 0.f;
            #pragma unroll
            for (int ot = 0; ot < 4; ot++)
                #pragma unroll
                for (int r = 0; r < 4; r++) {
                    int o = oh * 64 + ot * 16 + q * 4 + r;
                    float v = acc[ot][nt][r] + b2f(bias[o]);
                    v = gelu_f(v);
                    s += b2f(fc2w[o]) * v;
                }
            s += __shfl_xor(s, 16, 64);
            s += __shfl_xor(s, 32, 64);
            if (q == 0)
                psum[(size_t)oh * (Bb * Nn) + (size_t)b * Nn + n] = s;
        }
    } else {
        #pragma unroll
        for (int nt = 0; nt < 2; nt++) {
            int n = nbw + nt * 16 + lo;
            float mv = b2f(mask[(size_t)b * Nn + n]);
            #pragma unroll
            for (int ot = 0; ot < 4; ot++) {
                u16 hv[4] __attribute__((aligned(8)));
                #pragma unroll
                for (int r = 0; r < 4; r++) {
                    int o = oh * 64 + ot * 16 + q * 4 + r;
                    float v = acc[ot][nt][r] + b2f(bias[o]) + f0p[b * Cc + o] * mv;
                    if (EPI == 0) v = gelu_f(v);
                    hv[r] = f2b(v);
                }
                *(uint2*)&tr2[w][nt * 16 + lo][ot * 16 + q * 4] = *(const uint2*)hv;
            }
        }
        __syncthreads();
        #pragma unroll
        for (int it = 0; it < 4; it++) {
            int id = it * 64 + lane;
            int row = id >> 3, seg = id & 7;
            uint4 v4 = *(const uint4*)&tr2[w][row][seg * 8];
            *(uint4*)&hY[((size_t)b * Nn + nbw + row) * 128 + oh * 64 + seg * 8] = v4;
        }
        if (EPI == 0) {
            int c = oh * 64 + lane;
            const u16* wnp = wn + (size_t)b * Nn + nbw;
            u16 hvv[32] __attribute__((aligned(16)));
            #pragma unroll
            for (int j = 0; j < 32; j++)
                hvv[j] = f2b(b2f(tr2[w][j][lane]) * b2f(wnp[j]));
            u16* dstp = hw_cn + ((size_t)(b * Cc) + c) * Nn + nbw;
            #pragma unroll
            for (int i = 0; i < 4; i++)
                *(uint4*)(dstp + i * 8) = *(const uint4*)(hvv + i * 8);
        }
    }
}

// out = (psum0 + psum1 + fc2_b) * mask, dtype per flag
__global__ __launch_bounds__(256) void fc2_final(
    const float* __restrict__ psum, const u16* __restrict__ fc2b,
    const u16* __restrict__ mask, void* __restrict__ out, const int* __restrict__ flag) {
    int g = blockIdx.x * 256 + threadIdx.x;   // < Bb*Nn
    float s = psum[g] + psum[(size_t)Bb * Nn + g] + b2f(fc2b[0]);
    s *= b2f(mask[g]);
    if (*flag) ((u16*)out)[g] = f2b(s);
    else       ((float*)out)[g] = s;
}

extern "C" void kernel_launch(void* const* d_in, const int* in_sizes, int n_in,
                              void* d_out, int out_size, void* d_ws, size_t ws_size,
                              hipStream_t stream) {
    char* p = (char*)d_ws;
    auto alloc = [&](size_t bytes) { void* r = (void*)p; p += (bytes + 255) & ~(size_t)255; return r; };

    int* flag = (int*)alloc(256);

    SegTable tab;
    u16* nin[16];
    for (int i = 0; i < 16; i++) {
        tab.src[i] = d_in[i];
        if (i == 7 || i == 8) {
            nin[i] = (u16*)flag;
            tab.dst[i] = nin[i];
            tab.count[i] = 0;
        } else {
            int cnt = in_sizes[i];
            nin[i] = (u16*)alloc((size_t)cnt * 2);
            tab.dst[i] = nin[i];
            tab.count[i] = cnt;
        }
    }
    const u16* x      = nin[0];
    const u16* nodes  = nin[1];
    const u16* mask   = nin[2];
    const u16* wn     = nin[3];
    const u16* modes  = nin[4];
    const u16* fc0_w  = nin[5];
    const u16* fc0_b  = nin[6];
    const u16* w0n    = nin[9];
    const u16* conv_w = nin[10];
    const u16* conv_b = nin[11];
    const u16* fc1_w  = nin[12];
    const u16* fc1_b  = nin[13];
    const u16* fc2_w  = nin[14];
    const u16* fc2_b  = nin[15];

    u16* bigB   = (u16*)alloc((size_t)Bb * Nn * 256 * 2);        // 67.1 MB
    u16* hA     = (u16*)alloc((size_t)Bb * Nn * 128 * 2);        // 33.6 MB
    u16* hB     = (u16*)alloc((size_t)Bb * Nn * 128 * 2);        // 33.6 MB
    u16* hw_cn  = (u16*)alloc((size_t)Bb * Cc * Nn * 2);         // 33.6 MB
    u16* pxc    = (u16*)alloc((size_t)Bb * SPLIT * Cc * Kk * 2); // 8.4 MB
    u16* pps    = (u16*)alloc((size_t)Bb * SPLIT * Cc * Kk * 2); // 8.4 MB
    u16* wcTl   = (u16*)alloc((size_t)Kk * Cc * Cc * 2);         // 4.2 MB
    u16* wsTl   = (u16*)alloc((size_t)Kk * Cc * Cc * 2);         // 4.2 MB
    u16* w0T    = (u16*)alloc((size_t)Cc * Cc * 2);
    u16* xcT    = (u16*)alloc((size_t)Bb * Kk * Cc * 2);
    u16* psT    = (u16*)alloc((size_t)Bb * Kk * Cc * 2);
    float* x0f  = (float*)alloc((size_t)Bb * Cc * 4);
    u16* x0b    = (u16*)alloc((size_t)Bb * Cc * 2);
    float* f0f  = (float*)alloc((size_t)Bb * Cc * 4);
    u16* Ablk   = (u16*)alloc((size_t)Bb * 12 * 128 * 32 * 2);
    u16* Ablk1  = (u16*)alloc((size_t)4 * 128 * 32 * 2);
    float* psum = (float*)alloc((size_t)2 * Bb * Nn * 4);        // 1.0 MB
    // total ws ~= 198 MB (< 207 MB proven safe)

    const long ASTR = 12L * 128 * 32;

    detect_kernel<<<1, 64, 0, stream>>>((const unsigned int*)d_in[2], flag);
    convert_kernel<<<512, 256, 0, stream>>>(tab, flag);

    bases_nk_kernel<<<dim3(Nn / 64, Bb), 256, 0, stream>>>(nodes, modes, mask, bigB);
    fc0_nk_kernel<<<dim3(Nn / 64, Bb), 256, 0, stream>>>(x, fc0_w, fc0_b, wn, hA, hw_cn);

    u16* hX = hA;
    u16* hY = hB;
    for (int l = 0; l < Ll; l++) {
        transpose_w_layer<<<dim3(129), 256, 0, stream>>>(d_in[7], d_in[8], w0n, wcTl, wsTl, w0T, flag, l);
        x0_kernel<<<dim3(Cc, Bb), 256, 0, stream>>>(hw_cn, mask, x0f, x0b);
        proj_mfma<<<dim3(SPLIT, 2, Bb), 256, 0, stream>>>(hw_cn, nodes, modes, mask, pxc, pps);
        reduce_kernel<<<dim3((Bb * Cc * Kk) / 256), 256, 0, stream>>>(pxc, pps, xcT, psT);
        conv_fill<<<dim3(4, Bb), 256, 0, stream>>>(conv_w, Ablk, l);
        mix_mfma<<<dim3(129), 256, 0, stream>>>(xcT, psT, wcTl, wsTl, w0T, x0b, Ablk, f0f);
        if (l < Ll - 1) {
            combine_mfma<0, 12><<<dim3(Nn / 128, 2, Bb), 256, 0, stream>>>(
                Ablk, ASTR, bigB, hX, hY, hw_cn, f0f, conv_b + l * Cc, mask, wn, fc2_w, psum);
        } else {
            combine_mfma<1, 12><<<dim3(Nn / 128, 2, Bb), 256, 0, stream>>>(
                Ablk, ASTR, bigB, hX, hY, hw_cn, f0f, conv_b + l * Cc, mask, wn, fc2_w, psum);
        }
        u16* tmp = hX; hX = hY; hY = tmp;
    }

    buildA1_blk<<<dim3(4), 256, 0, stream>>>(fc1_w, Ablk1);
    combine_mfma<2, 4><<<dim3(Nn / 128, 2, Bb), 256, 0, stream>>>(
        Ablk1, 0L, bigB, hX, hY, hw_cn, f0f, fc1_b, mask, wn, fc2_w, psum);
    fc2_final<<<dim3((Bb * Nn) / 256), 256, 0, stream>>>(psum, fc2_b, mask, d_out, flag);
}

// Round 8
// 773.035 us; speedup vs baseline: 2.4866x; 1.0527x over previous
//
#include <hip/hip_runtime.h>

using u16 = unsigned short;
typedef short bf8 __attribute__((ext_vector_type(8)));
typedef float f4 __attribute__((ext_vector_type(4)));

constexpr int Bb = 8;
constexpr int Nn = 16384;
constexpr int Kk = 128;
constexpr int Cc = 128;
constexpr int Ll = 4;
constexpr int SPLIT = 32;

__device__ __forceinline__ float b2f(u16 u) {
    union { unsigned int i; float f; } v; v.i = ((unsigned int)u) << 16; return v.f;
}
__device__ __forceinline__ u16 f2b(float f) {
    union { float f; unsigned int i; } v; v.f = f;
    unsigned int i = v.i;
    return (u16)((i + 0x7fffu + ((i >> 16) & 1u)) >> 16);
}
__device__ __forceinline__ float gelu_f(float x) {
    return 0.5f * x * (1.0f + erff(x * 0.70710678118654752f));
}

// ---- dtype detection + input normalization ----
__global__ void detect_kernel(const unsigned int* __restrict__ maskw, int* __restrict__ flag) {
    if (threadIdx.x == 0 && blockIdx.x == 0)
        *flag = ((maskw[0] & 0xFFFFu) != 0u) ? 1 : 0;   // 1 = inputs are bf16
}

struct SegTable {
    const void* src[16];
    u16* dst[16];
    int count[16];
};

__global__ __launch_bounds__(256) void convert_kernel(SegTable t, const int* __restrict__ flag) {
    const int f = *flag;
    const int stride = gridDim.x * 256;
    for (int seg = 0; seg < 16; ++seg) {
        const int cnt = t.count[seg];
        const void* s = t.src[seg];
        u16* d = t.dst[seg];
        for (int i = blockIdx.x * 256 + threadIdx.x; i < cnt; i += stride) {
            d[i] = f ? ((const u16*)s)[i] : f2b(((const float*)s)[i]);
        }
    }
}

// bigB[b][n][0:128]=cos*mask, [128:256]=sin*mask
__global__ __launch_bounds__(256) void bases_nk_kernel(
    const u16* __restrict__ nodes, const u16* __restrict__ modes,
    const u16* __restrict__ mask, u16* __restrict__ bigB) {
    int t = threadIdx.x;
    int nl = t >> 2, kp = t & 3;
    int n = blockIdx.x * 64 + nl, b = blockIdx.y;
    float nx = b2f(nodes[((size_t)(b * Nn + n)) * 2]);
    float ny = b2f(nodes[((size_t)(b * Nn + n)) * 2 + 1]);
    float mk = b2f(mask[b * Nn + n]);
    u16 cb[32] __attribute__((aligned(16)));
    u16 sb[32] __attribute__((aligned(16)));
    #pragma unroll
    for (int j = 0; j < 32; j++) {
        int k = kp * 32 + j;
        float m0 = b2f(modes[k * 2]), m1 = b2f(modes[k * 2 + 1]);
        float tt = nx * m0 + ny * m1;
        cb[j] = f2b(__cosf(tt) * mk);
        sb[j] = f2b(__sinf(tt) * mk);
    }
    u16* row = bigB + ((size_t)b * Nn + n) * 256;
    #pragma unroll
    for (int i = 0; i < 4; i++) {
        *(uint4*)(row + kp * 32 + i * 8)       = *(const uint4*)(cb + i * 8);
        *(uint4*)(row + 128 + kp * 32 + i * 8) = *(const uint4*)(sb + i * 8);
    }
}

// h into hA[b][n][128]; hw_cn[b][c][n] = h*wn
__global__ __launch_bounds__(256) void fc0_nk_kernel(
    const u16* __restrict__ x, const u16* __restrict__ fc0_w,
    const u16* __restrict__ fc0_b, const u16* __restrict__ wn,
    u16* __restrict__ hA, u16* __restrict__ hw_cn) {
    int t = threadIdx.x;
    int nl = t >> 2, cp = t & 3;
    int n = blockIdx.x * 64 + nl, b = blockIdx.y;
    const u16* xp = x + ((size_t)(b * Nn + n)) * 3;
    float x0v = b2f(xp[0]), x1v = b2f(xp[1]), x2v = b2f(xp[2]);
    float wv = b2f(wn[b * Nn + n]);
    u16 hb[32] __attribute__((aligned(16)));
    #pragma unroll
    for (int j = 0; j < 32; j++) {
        int c = cp * 32 + j;
        float acc = b2f(fc0_b[c]);
        acc += x0v * b2f(fc0_w[0 * Cc + c]);
        acc += x1v * b2f(fc0_w[1 * Cc + c]);
        acc += x2v * b2f(fc0_w[2 * Cc + c]);
        hb[j] = f2b(acc);
        hw_cn[((size_t)(b * Cc + c)) * Nn + n] = f2b(acc * wv);
    }
    u16* row = hA + ((size_t)b * Nn + n) * 128 + cp * 32;
    #pragma unroll
    for (int i = 0; i < 4; i++) *(uint4*)(row + i * 8) = *(const uint4*)(hb + i * 8);
}

// hw_cn[b][c][n] = h[b][n][c] * wn[b][n]   (64n x 128c tile via LDS)
__global__ __launch_bounds__(256) void hw_transpose(
    const u16* __restrict__ h, const u16* __restrict__ wn, u16* __restrict__ hw_cn) {
    __shared__ u16 lds[64][136];
    int nb = blockIdx.x * 64, b = blockIdx.y, t = threadIdx.x;
    #pragma unroll
    for (int i = 0; i < 4; i++) {
        int id = i * 256 + t;
        int row = id >> 4, ch = id & 15;
        int n = nb + row;
        uint4 v = *(const uint4*)&h[((size_t)b * Nn + n) * 128 + ch * 8];
        float wv = b2f(wn[(size_t)b * Nn + n]);
        const u16* pv = (const u16*)&v;
        u16 o8[8] __attribute__((aligned(16)));
        #pragma unroll
        for (int j = 0; j < 8; j++) o8[j] = f2b(b2f(pv[j]) * wv);
        *(uint4*)&lds[row][ch * 8] = *(const uint4*)o8;
    }
    __syncthreads();
    int c = t >> 1, half = t & 1;
    u16 outv[32] __attribute__((aligned(16)));
    #pragma unroll
    for (int j = 0; j < 32; j++) outv[j] = lds[half * 32 + j][c];
    u16* dst = hw_cn + ((size_t)(b * Cc + c)) * Nn + nb + half * 32;
    #pragma unroll
    for (int i = 0; i < 4; i++) *(uint4*)(dst + i * 8) = *(const uint4*)(outv + i * 8);
}

// per-layer: wcTl/wsTl[k][o][i] bf16 from raw [l][i][o][k]; w0T[o][i]
__global__ __launch_bounds__(256) void transpose_w_layer(
    const void* __restrict__ wcraw, const void* __restrict__ wsraw,
    const u16* __restrict__ w0n,
    u16* __restrict__ wcTl, u16* __restrict__ wsTl, u16* __restrict__ w0T,
    const int* __restrict__ flag, int l) {
    __shared__ u16 tile[128][136];
    int o = blockIdx.x, t = threadIdx.x;
    const int f = *flag;
    if (o == 128) {
        int i = t >> 1, oh = (t & 1) * 64;
        #pragma unroll
        for (int j = 0; j < 64; j += 8)
            *(uint4*)&tile[i][oh + j] = *(const uint4*)(w0n + ((size_t)(l * 128 + i)) * 128 + oh + j);
        __syncthreads();
        int o2 = t >> 1, ih = (t & 1) * 64;
        u16 buf[64] __attribute__((aligned(16)));
        #pragma unroll
        for (int j = 0; j < 64; j++) buf[j] = tile[ih + j][o2];
        #pragma unroll
        for (int j = 0; j < 64; j += 8)
            *(uint4*)(w0T + (size_t)o2 * 128 + ih + j) = *(const uint4*)(buf + j);
        return;
    }
    for (int wsel = 0; wsel < 2; wsel++) {
        if (wsel) __syncthreads();
        const void* raw = wsel ? wsraw : wcraw;
        u16* dst = wsel ? wsTl : wcTl;
        int i = t >> 1, kh = (t & 1) * 64;
        size_t base = (((size_t)(l * 128 + i)) * 128 + o) * 128 + kh;
        if (f) {
            #pragma unroll
            for (int j = 0; j < 64; j += 8)
                *(uint4*)&tile[i][kh + j] = *(const uint4*)((const u16*)raw + base + j);
        } else {
            #pragma unroll
            for (int j = 0; j < 64; j += 4) {
                float4 v = *(const float4*)((const float*)raw + base + j);
                u16 o4[4] __attribute__((aligned(8))) = { f2b(v.x), f2b(v.y), f2b(v.z), f2b(v.w) };
                *(unsigned long long*)&tile[i][kh + j] = *(const unsigned long long*)o4;
            }
        }
        __syncthreads();
        int k = t >> 1, ih = (t & 1) * 64;
        u16 buf[64] __attribute__((aligned(16)));
        #pragma unroll
        for (int j = 0; j < 64; j++) buf[j] = tile[ih + j][k];
        #pragma unroll
        for (int j = 0; j < 64; j += 8)
            *(uint4*)(dst + ((size_t)k * 128 + o) * 128 + ih + j) = *(const uint4*)(buf + j);
    }
}

// x0[b,c] = sum_n hw[b,c,n]*mask[b,n]
__global__ __launch_bounds__(256) void x0_kernel(
    const u16* __restrict__ hw, const u16* __restrict__ mask,
    float* __restrict__ x0, u16* __restrict__ x0b) {
    int c = blockIdx.x, b = blockIdx.y;
    const u16* row = hw + ((size_t)(b * Cc + c)) * Nn;
    const u16* mrow = mask + (size_t)b * Nn;
    float acc = 0.f;
    for (int n = threadIdx.x; n < Nn; n += 256) acc += b2f(row[n]) * b2f(mrow[n]);
    __shared__ float red[4];
    for (int off = 32; off; off >>= 1) acc += __shfl_down(acc, off, 64);
    if ((threadIdx.x & 63) == 0) red[threadIdx.x >> 6] = acc;
    __syncthreads();
    if (threadIdx.x == 0) {
        float v = red[0] + red[1] + red[2] + red[3];
        x0[b * Cc + c] = v;
        x0b[b * Cc + c] = f2b(v);
    }
}

// MFMA projection, fast on-the-fly bases; bf16 partials [b][s][k][c]
__global__ __launch_bounds__(256) void proj_mfma(
    const u16* __restrict__ hw, const u16* __restrict__ nodes,
    const u16* __restrict__ modes, const u16* __restrict__ mask,
    u16* __restrict__ pxc, u16* __restrict__ pps) {
    int s = blockIdx.x, kh = blockIdx.y, b = blockIdx.z;
    int w = threadIdx.x >> 6, lane = threadIdx.x & 63;
    int lo = lane & 15, q = lane >> 4;
    int n0 = s * 512;
    int kmode = kh * 64 + w * 16 + lo;
    float m0 = b2f(modes[kmode * 2]), m1 = b2f(modes[kmode * 2 + 1]);
    const u16* ap[8];
    #pragma unroll
    for (int ct = 0; ct < 8; ct++)
        ap[ct] = hw + ((size_t)(b * Cc) + ct * 16 + lo) * Nn + n0 + q * 8;
    const u16* np = nodes + ((size_t)(b * Nn) + n0 + q * 8) * 2;
    const u16* mp = mask + (size_t)b * Nn + n0 + q * 8;
    f4 aC[8] = {}, aS[8] = {};
    for (int js = 0; js < 16; js++) {
        int off = js * 32;
        uint4 nq0 = *(const uint4*)(np + off * 2);
        uint4 nq1 = *(const uint4*)(np + off * 2 + 8);
        uint4 mq  = *(const uint4*)(mp + off);
        float xs[8], ys[8], mk[8];
        xs[0] = b2f(nq0.x & 0xffffu); ys[0] = b2f(nq0.x >> 16);
        xs[1] = b2f(nq0.y & 0xffffu); ys[1] = b2f(nq0.y >> 16);
        xs[2] = b2f(nq0.z & 0xffffu); ys[2] = b2f(nq0.z >> 16);
        xs[3] = b2f(nq0.w & 0xffffu); ys[3] = b2f(nq0.w >> 16);
        xs[4] = b2f(nq1.x & 0xffffu); ys[4] = b2f(nq1.x >> 16);
        xs[5] = b2f(nq1.y & 0xffffu); ys[5] = b2f(nq1.y >> 16);
        xs[6] = b2f(nq1.z & 0xffffu); ys[6] = b2f(nq1.z >> 16);
        xs[7] = b2f(nq1.w & 0xffffu); ys[7] = b2f(nq1.w >> 16);
        mk[0] = b2f(mq.x & 0xffffu);  mk[1] = b2f(mq.x >> 16);
        mk[2] = b2f(mq.y & 0xffffu);  mk[3] = b2f(mq.y >> 16);
        mk[4] = b2f(mq.z & 0xffffu);  mk[5] = b2f(mq.z >> 16);
        mk[6] = b2f(mq.w & 0xffffu);  mk[7] = b2f(mq.w >> 16);
        u16 cf[8] __attribute__((aligned(16)));
        u16 sf[8] __attribute__((aligned(16)));
        #pragma unroll
        for (int j = 0; j < 8; j++) {
            float tt = xs[j] * m0 + ys[j] * m1;
            cf[j] = f2b(__cosf(tt) * mk[j]);
            sf[j] = f2b(__sinf(tt) * mk[j]);
        }
        bf8 cv = *(const bf8*)cf;
        bf8 sv = *(const bf8*)sf;
        #pragma unroll
        for (int ct = 0; ct < 8; ct++) {
            bf8 av = *(const bf8*)(ap[ct] + off);
            aC[ct] = __builtin_amdgcn_mfma_f32_16x16x32_bf16(av, cv, aC[ct], 0, 0, 0);
            aS[ct] = __builtin_amdgcn_mfma_f32_16x16x32_bf16(av, sv, aS[ct], 0, 0, 0);
        }
    }
    size_t base = ((size_t)(b * SPLIT + s)) * 16384 + (size_t)kmode * 128;
    #pragma unroll
    for (int ct = 0; ct < 8; ct++) {
        u16 pc[4] __attribute__((aligned(8)));
        u16 pssv[4] __attribute__((aligned(8)));
        #pragma unroll
        for (int r = 0; r < 4; r++) { pc[r] = f2b(aC[ct][r]); pssv[r] = f2b(aS[ct][r]); }
        *(uint2*)&pxc[base + ct * 16 + q * 4] = *(const uint2*)pc;
        *(uint2*)&pps[base + ct * 16 + q * 4] = *(const uint2*)pssv;
    }
}

// sum bf16 partials over s -> bf16 xcT/psT [b][k][c]
__global__ __launch_bounds__(256) void reduce_kernel(
    const u16* __restrict__ pxc, const u16* __restrict__ pps,
    u16* __restrict__ xcT, u16* __restrict__ psT) {
    int g = blockIdx.x * 256 + threadIdx.x;
    int b = g >> 14, r = g & 16383;
    const u16* p1 = pxc + ((size_t)b * SPLIT) * 16384 + r;
    const u16* p2 = pps + ((size_t)b * SPLIT) * 16384 + r;
    float a1 = 0.f, a2 = 0.f;
    #pragma unroll
    for (int s2 = 0; s2 < SPLIT; s2++) {
        a1 += b2f(p1[(size_t)s2 * 16384]);
        a2 += b2f(p2[(size_t)s2 * 16384]);
    }
    xcT[g] = f2b(a1); psT[g] = f2b(a2);
}

// MFMA mix: per mode k, U[16][i]=[xc(b);ps(b)], -> Ablk (+f0 block kb==128)
__global__ __launch_bounds__(256) void mix_mfma(
    const u16* __restrict__ xcT, const u16* __restrict__ psT,
    const u16* __restrict__ wcTl, const u16* __restrict__ wsTl,
    const u16* __restrict__ w0T, const u16* __restrict__ x0b,
    u16* __restrict__ Ablk, float* __restrict__ f0p) {
    int kb = blockIdx.x;
    int w = threadIdx.x >> 6, lane = threadIdx.x & 63;
    int lo = lane & 15, q = lane >> 4;
    if (kb == 128) {
        const u16* Arow = x0b + (lo & 7) * 128 + q * 8;
        f4 acc[2] = {};
        #pragma unroll
        for (int step = 0; step < 4; step++) {
            bf8 av = *(const bf8*)(Arow + step * 32);
            #pragma unroll
            for (int nt = 0; nt < 2; nt++) {
                int o = w * 32 + nt * 16 + lo;
                bf8 bv = *(const bf8*)(w0T + (size_t)o * 128 + q * 8 + step * 32);
                acc[nt] = __builtin_amdgcn_mfma_f32_16x16x32_bf16(av, bv, acc[nt], 0, 0, 0);
            }
        }
        if (q < 2) {
            #pragma unroll
            for (int nt = 0; nt < 2; nt++)
                #pragma unroll
                for (int r = 0; r < 4; r++) {
                    int bb = q * 4 + r, o = w * 32 + nt * 16 + lo;
                    f0p[bb * 128 + o] = acc[nt][r];
                }
        }
        return;
    }
    int k = kb;
    const u16* Arow = (lo < 8)
        ? xcT + ((size_t)(lo * 128 + k)) * 128 + q * 8
        : psT + ((size_t)((lo - 8) * 128 + k)) * 128 + q * 8;
    const u16* wc_l = wcTl + (size_t)k * (128 * 128);
    const u16* ws_l = wsTl + (size_t)k * (128 * 128);
    f4 accC[2] = {}, accS[2] = {};
    #pragma unroll
    for (int step = 0; step < 4; step++) {
        bf8 av = *(const bf8*)(Arow + step * 32);
        #pragma unroll
        for (int nt = 0; nt < 2; nt++) {
            int o = w * 32 + nt * 16 + lo;
            bf8 bc = *(const bf8*)(wc_l + (size_t)o * 128 + q * 8 + step * 32);
            bf8 bs = *(const bf8*)(ws_l + (size_t)o * 128 + q * 8 + step * 32);
            accC[nt] = __builtin_amdgcn_mfma_f32_16x16x32_bf16(av, bc, accC[nt], 0, 0, 0);
            accS[nt] = __builtin_amdgcn_mfma_f32_16x16x32_bf16(av, bs, accS[nt], 0, 0, 0);
        }
    }
    #pragma unroll
    for (int nt = 0; nt < 2; nt++)
        #pragma unroll
        for (int r = 0; r < 4; r++) {
            float uc = accC[nt][r], us = accS[nt][r];
            float ucp = __shfl_xor(uc, 32, 64);
            float usp = __shfl_xor(us, 32, 64);
            if (q < 2) {
                int bb = q * 4 + r, o = w * 32 + nt * 16 + lo;
                float fcv = uc + usp;
                float fsv = us - ucp;
                Ablk[(((size_t)(bb * 12 + (k >> 5))) * 128 + o) * 32 + (k & 31)] = f2b(2.f * fcv);
                Ablk[(((size_t)(bb * 12 + 4 + (k >> 5))) * 128 + o) * 32 + (k & 31)] = f2b(-2.f * fsv);
            }
        }
}

// fill Ablk conv segment (ks 8..11)
__global__ __launch_bounds__(256) void conv_fill(
    const u16* __restrict__ conv_w, u16* __restrict__ Ablk, int l) {
    int ks2 = blockIdx.x, b = blockIdx.y, t = threadIdx.x;
    int o = t >> 1, half = t & 1;
    const u16* src = conv_w + ((size_t)(l * 128 + o)) * 128 + ks2 * 32 + half * 16;
    u16* dst = Ablk + (((size_t)(b * 12 + 8 + ks2)) * 128 + o) * 32 + half * 16;
    *(uint4*)dst = *(const uint4*)src;
    *(uint4*)(dst + 8) = *(const uint4*)(src + 8);
}

// Ablk1[ks(4)][o(128)][32] = fc1_w^T
__global__ __launch_bounds__(256) void buildA1_blk(
    const u16* __restrict__ fc1_w, u16* __restrict__ Ablk1) {
    int ks = blockIdx.x, t = threadIdx.x;
    int o = t >> 1, half = t & 1;
    u16 ov[16] __attribute__((aligned(16)));
    #pragma unroll
    for (int j = 0; j < 16; j++) {
        int kk = ks * 32 + half * 16 + j;
        ov[j] = fc1_w[kk * 128 + o];
    }
    u16* dst = Ablk1 + ((size_t)ks * 128 + o) * 32 + half * 16;
    *(uint4*)dst = *(const uint4*)ov;
    *(uint4*)(dst + 8) = *(const uint4*)(ov + 8);
}

// MFMA combine v4: LDS-staged GEMM. Block 128o x 128n, 4 waves of 64o x 64n,
// K = NKS*32, double-buffered 8KB A + 8KB B LDS tiles (rows padded to 80B).
// EPI 0: gelu, write hY. EPI 1: no gelu, write hY. EPI 2: fc1 gelu + fc2 partial -> psum.
template <int EPI, int NKS>
__global__ __launch_bounds__(256) void combine_mfma(
    const u16* __restrict__ Ablk, long astr,
    const u16* __restrict__ bigB, const u16* __restrict__ hX,
    u16* __restrict__ hY,
    const float* __restrict__ f0p, const u16* __restrict__ bias,
    const u16* __restrict__ mask,
    const u16* __restrict__ fc2w, float* __restrict__ psum) {
    __shared__ u16 lds[20480];   // 40 KB: A0 A1 B0 B1 (128 rows x 40 u16 each)
    int b = blockIdx.y;
    int nb = blockIdx.x * 128;
    int t = threadIdx.x;
    int w = t >> 6, lane = t & 63;
    int lo = lane & 15, q = lane >> 4;
    int wo = (w & 1) * 64, wn2 = (w >> 1) * 64;

    u16* abuf[2] = { lds, lds + 5120 };
    u16* bbuf[2] = { lds + 10240, lds + 15360 };

    const u16* Ab = Ablk + (size_t)b * astr;
    int so = t >> 1, sh = t & 1;
    size_t brow = (size_t)b * Nn + nb + so;
    const u16* bigRow = bigB + brow * 256 + sh * 16;
    const u16* hRow   = hX   + brow * 128 + sh * 16;

    uint4 ra0, ra1, rb0, rb1;
    auto loadGlob = [&](int ksn, uint4& a0, uint4& a1, uint4& b0, uint4& b1) {
        const u16* asrc = Ab + (size_t)ksn * 4096 + so * 32 + sh * 16;
        a0 = *(const uint4*)asrc;
        a1 = *(const uint4*)(asrc + 8);
        const u16* bsrc;
        if (EPI == 2) bsrc = hRow + ksn * 32;
        else bsrc = (ksn < 8) ? (bigRow + ksn * 32) : (hRow + (ksn - 8) * 32);
        b0 = *(const uint4*)bsrc;
        b1 = *(const uint4*)(bsrc + 8);
    };
    auto stash = [&](int pb, uint4 a0, uint4 a1, uint4 b0, uint4 b1) {
        u16* ad = abuf[pb] + so * 40 + sh * 16;
        *(uint4*)ad = a0; *(uint4*)(ad + 8) = a1;
        u16* bd = bbuf[pb] + so * 40 + sh * 16;
        *(uint4*)bd = b0; *(uint4*)(bd + 8) = b1;
    };

    loadGlob(0, ra0, ra1, rb0, rb1);
    stash(0, ra0, ra1, rb0, rb1);
    f4 acc[4][4] = {};
    #pragma unroll
    for (int ks = 0; ks < NKS; ks++) {
        __syncthreads();
        if (ks + 1 < NKS) loadGlob(ks + 1, ra0, ra1, rb0, rb1);
        int pb = ks & 1;
        bf8 avf[4], bvf[4];
        #pragma unroll
        for (int ot = 0; ot < 4; ot++)
            avf[ot] = *(const bf8*)(abuf[pb] + (wo + ot * 16 + lo) * 40 + q * 8);
        #pragma unroll
        for (int nt = 0; nt < 4; nt++)
            bvf[nt] = *(const bf8*)(bbuf[pb] + (wn2 + nt * 16 + lo) * 40 + q * 8);
        #pragma unroll
        for (int ot = 0; ot < 4; ot++)
            #pragma unroll
            for (int nt = 0; nt < 4; nt++)
                acc[ot][nt] = __builtin_amdgcn_mfma_f32_16x16x32_bf16(avf[ot], bvf[nt], acc[ot][nt], 0, 0, 0);
        if (ks + 1 < NKS) stash(1 - pb, ra0, ra1, rb0, rb1);
    }
    __syncthreads();

    if (EPI == 2) {
        #pragma unroll
        for (int nt = 0; nt < 4; nt++) {
            int n = nb + wn2 + nt * 16 + lo;
            float s = 0.f;
            #pragma unroll
            for (int ot = 0; ot < 4; ot++)
                #pragma unroll
                for (int r = 0; r < 4; r++) {
                    int o = wo + ot * 16 + q * 4 + r;
                    float v = acc[ot][nt][r] + b2f(bias[o]);
                    v = gelu_f(v);
                    s += b2f(fc2w[o]) * v;
                }
            s += __shfl_xor(s, 16, 64);
            s += __shfl_xor(s, 32, 64);
            if (q == 0)
                psum[(size_t)(w & 1) * (Bb * Nn) + (size_t)b * Nn + n] = s;
        }
    } else {
        u16* tile = lds + w * 4352;   // 64 x 68
        #pragma unroll
        for (int nt = 0; nt < 4; nt++) {
            int n = nb + wn2 + nt * 16 + lo;
            float mv = b2f(mask[(size_t)b * Nn + n]);
            #pragma unroll
            for (int ot = 0; ot < 4; ot++) {
                u16 hv[4] __attribute__((aligned(8)));
                #pragma unroll
                for (int r = 0; r < 4; r++) {
                    int o = wo + ot * 16 + q * 4 + r;
                    float v = acc[ot][nt][r] + b2f(bias[o]) + f0p[b * Cc + o] * mv;
                    if (EPI == 0) v = gelu_f(v);
                    hv[r] = f2b(v);
                }
                *(uint2*)&tile[(nt * 16 + lo) * 68 + ot * 16 + q * 4] = *(const uint2*)hv;
            }
        }
        __syncthreads();
        #pragma unroll
        for (int it = 0; it < 8; it++) {
            int row = it * 8 + (lane >> 3), seg = lane & 7;
            uint4 v4 = *(const uint4*)&tile[row * 68 + seg * 8];
            *(uint4*)&hY[((size_t)b * Nn + nb + wn2 + row) * 128 + wo + seg * 8] = v4;
        }
    }
}

// out = (psum0 + psum1 + fc2_b) * mask, dtype per flag
__global__ __launch_bounds__(256) void fc2_final(
    const float* __restrict__ psum, const u16* __restrict__ fc2b,
    const u16* __restrict__ mask, void* __restrict__ out, const int* __restrict__ flag) {
    int g = blockIdx.x * 256 + threadIdx.x;   // < Bb*Nn
    float s = psum[g] + psum[(size_t)Bb * Nn + g] + b2f(fc2b[0]);
    s *= b2f(mask[g]);
    if (*flag) ((u16*)out)[g] = f2b(s);
    else       ((float*)out)[g] = s;
}

extern "C" void kernel_launch(void* const* d_in, const int* in_sizes, int n_in,
                              void* d_out, int out_size, void* d_ws, size_t ws_size,
                              hipStream_t stream) {
    char* p = (char*)d_ws;
    auto alloc = [&](size_t bytes) { void* r = (void*)p; p += (bytes + 255) & ~(size_t)255; return r; };

    int* flag = (int*)alloc(256);

    SegTable tab;
    u16* nin[16];
    for (int i = 0; i < 16; i++) {
        tab.src[i] = d_in[i];
        if (i == 7 || i == 8) {
            nin[i] = (u16*)flag;
            tab.dst[i] = nin[i];
            tab.count[i] = 0;
        } else {
            int cnt = in_sizes[i];
            nin[i] = (u16*)alloc((size_t)cnt * 2);
            tab.dst[i] = nin[i];
            tab.count[i] = cnt;
        }
    }
    const u16* x      = nin[0];
    const u16* nodes  = nin[1];
    const u16* mask   = nin[2];
    const u16* wn     = nin[3];
    const u16* modes  = nin[4];
    const u16* fc0_w  = nin[5];
    const u16* fc0_b  = nin[6];
    const u16* w0n    = nin[9];
    const u16* conv_w = nin[10];
    const u16* conv_b = nin[11];
    const u16* fc1_w  = nin[12];
    const u16* fc1_b  = nin[13];
    const u16* fc2_w  = nin[14];
    const u16* fc2_b  = nin[15];

    u16* bigB   = (u16*)alloc((size_t)Bb * Nn * 256 * 2);        // 67.1 MB
    u16* hA     = (u16*)alloc((size_t)Bb * Nn * 128 * 2);        // 33.6 MB
    u16* hB     = (u16*)alloc((size_t)Bb * Nn * 128 * 2);        // 33.6 MB
    u16* hw_cn  = (u16*)alloc((size_t)Bb * Cc * Nn * 2);         // 33.6 MB
    u16* pxc    = (u16*)alloc((size_t)Bb * SPLIT * Cc * Kk * 2); // 8.4 MB
    u16* pps    = (u16*)alloc((size_t)Bb * SPLIT * Cc * Kk * 2); // 8.4 MB
    u16* wcTl   = (u16*)alloc((size_t)Kk * Cc * Cc * 2);         // 4.2 MB
    u16* wsTl   = (u16*)alloc((size_t)Kk * Cc * Cc * 2);         // 4.2 MB
    u16* w0T    = (u16*)alloc((size_t)Cc * Cc * 2);
    u16* xcT    = (u16*)alloc((size_t)Bb * Kk * Cc * 2);
    u16* psT    = (u16*)alloc((size_t)Bb * Kk * Cc * 2);
    float* x0f  = (float*)alloc((size_t)Bb * Cc * 4);
    u16* x0b    = (u16*)alloc((size_t)Bb * Cc * 2);
    float* f0f  = (float*)alloc((size_t)Bb * Cc * 4);
    u16* Ablk   = (u16*)alloc((size_t)Bb * 12 * 128 * 32 * 2);
    u16* Ablk1  = (u16*)alloc((size_t)4 * 128 * 32 * 2);
    float* psum = (float*)alloc((size_t)2 * Bb * Nn * 4);        // 1.0 MB
    // total ws ~= 198 MB

    const long ASTR = 12L * 128 * 32;

    detect_kernel<<<1, 64, 0, stream>>>((const unsigned int*)d_in[2], flag);
    convert_kernel<<<512, 256, 0, stream>>>(tab, flag);

    bases_nk_kernel<<<dim3(Nn / 64, Bb), 256, 0, stream>>>(nodes, modes, mask, bigB);
    fc0_nk_kernel<<<dim3(Nn / 64, Bb), 256, 0, stream>>>(x, fc0_w, fc0_b, wn, hA, hw_cn);

    u16* hX = hA;
    u16* hY = hB;
    for (int l = 0; l < Ll; l++) {
        transpose_w_layer<<<dim3(129), 256, 0, stream>>>(d_in[7], d_in[8], w0n, wcTl, wsTl, w0T, flag, l);
        x0_kernel<<<dim3(Cc, Bb), 256, 0, stream>>>(hw_cn, mask, x0f, x0b);
        proj_mfma<<<dim3(SPLIT, 2, Bb), 256, 0, stream>>>(hw_cn, nodes, modes, mask, pxc, pps);
        reduce_kernel<<<dim3((Bb * Cc * Kk) / 256), 256, 0, stream>>>(pxc, pps, xcT, psT);
        conv_fill<<<dim3(4, Bb), 256, 0, stream>>>(conv_w, Ablk, l);
        mix_mfma<<<dim3(129), 256, 0, stream>>>(xcT, psT, wcTl, wsTl, w0T, x0b, Ablk, f0f);
        if (l < Ll - 1) {
            combine_mfma<0, 12><<<dim3(Nn / 128, Bb), 256, 0, stream>>>(
                Ablk, ASTR, bigB, hX, hY, f0f, conv_b + l * Cc, mask, fc2_w, psum);
            hw_transpose<<<dim3(Nn / 64, Bb), 256, 0, stream>>>(hY, wn, hw_cn);
        } else {
            combine_mfma<1, 12><<<dim3(Nn / 128, Bb), 256, 0, stream>>>(
                Ablk, ASTR, bigB, hX, hY, f0f, conv_b + l * Cc, mask, fc2_w, psum);
        }
        u16* tmp = hX; hX = hY; hY = tmp;
    }

    buildA1_blk<<<dim3(4), 256, 0, stream>>>(fc1_w, Ablk1);
    combine_mfma<2, 4><<<dim3(Nn / 128, Bb), 256, 0, stream>>>(
        Ablk1, 0L, bigB, hX, hY, f0f, fc1_b, mask, fc2_w, psum);
    fc2_final<<<dim3((Bb * Nn) / 256), 256, 0, stream>>>(psum, fc2_b, mask, d_out, flag);
}

// Round 9
// 705.713 us; speedup vs baseline: 2.7238x; 1.0954x over previous
//
#include <hip/hip_runtime.h>

using u16 = unsigned short;
typedef short bf8 __attribute__((ext_vector_type(8)));
typedef float f4 __attribute__((ext_vector_type(4)));

constexpr int Bb = 8;
constexpr int Nn = 16384;
constexpr int Kk = 128;
constexpr int Cc = 128;
constexpr int Ll = 4;
constexpr int SPLIT = 32;

__device__ __forceinline__ float b2f(u16 u) {
    union { unsigned int i; float f; } v; v.i = ((unsigned int)u) << 16; return v.f;
}
__device__ __forceinline__ u16 f2b(float f) {
    union { float f; unsigned int i; } v; v.f = f;
    unsigned int i = v.i;
    return (u16)((i + 0x7fffu + ((i >> 16) & 1u)) >> 16);
}
__device__ __forceinline__ float gelu_f(float x) {
    return 0.5f * x * (1.0f + erff(x * 0.70710678118654752f));
}

// ---- dtype detection + input normalization ----
__global__ void detect_kernel(const unsigned int* __restrict__ maskw, int* __restrict__ flag) {
    if (threadIdx.x == 0 && blockIdx.x == 0)
        *flag = ((maskw[0] & 0xFFFFu) != 0u) ? 1 : 0;   // 1 = inputs are bf16
}

struct SegTable {
    const void* src[16];
    u16* dst[16];
    int count[16];
};

__global__ __launch_bounds__(256) void convert_kernel(SegTable t, const int* __restrict__ flag) {
    const int f = *flag;
    const int stride = gridDim.x * 256;
    for (int seg = 0; seg < 16; ++seg) {
        const int cnt = t.count[seg];
        const void* s = t.src[seg];
        u16* d = t.dst[seg];
        for (int i = blockIdx.x * 256 + threadIdx.x; i < cnt; i += stride) {
            d[i] = f ? ((const u16*)s)[i] : f2b(((const float*)s)[i]);
        }
    }
}

// bigB[b][n][0:128]=cos*mask, [128:256]=sin*mask
__global__ __launch_bounds__(256) void bases_nk_kernel(
    const u16* __restrict__ nodes, const u16* __restrict__ modes,
    const u16* __restrict__ mask, u16* __restrict__ bigB) {
    int t = threadIdx.x;
    int nl = t >> 2, kp = t & 3;
    int n = blockIdx.x * 64 + nl, b = blockIdx.y;
    float nx = b2f(nodes[((size_t)(b * Nn + n)) * 2]);
    float ny = b2f(nodes[((size_t)(b * Nn + n)) * 2 + 1]);
    float mk = b2f(mask[b * Nn + n]);
    u16 cb[32] __attribute__((aligned(16)));
    u16 sb[32] __attribute__((aligned(16)));
    #pragma unroll
    for (int j = 0; j < 32; j++) {
        int k = kp * 32 + j;
        float m0 = b2f(modes[k * 2]), m1 = b2f(modes[k * 2 + 1]);
        float tt = nx * m0 + ny * m1;
        cb[j] = f2b(__cosf(tt) * mk);
        sb[j] = f2b(__sinf(tt) * mk);
    }
    u16* row = bigB + ((size_t)b * Nn + n) * 256;
    #pragma unroll
    for (int i = 0; i < 4; i++) {
        *(uint4*)(row + kp * 32 + i * 8)       = *(const uint4*)(cb + i * 8);
        *(uint4*)(row + 128 + kp * 32 + i * 8) = *(const uint4*)(sb + i * 8);
    }
}

// h into hA[b][n][128]; hw_cn[b][c][n] = h*wn
__global__ __launch_bounds__(256) void fc0_nk_kernel(
    const u16* __restrict__ x, const u16* __restrict__ fc0_w,
    const u16* __restrict__ fc0_b, const u16* __restrict__ wn,
    u16* __restrict__ hA, u16* __restrict__ hw_cn) {
    int t = threadIdx.x;
    int nl = t >> 2, cp = t & 3;
    int n = blockIdx.x * 64 + nl, b = blockIdx.y;
    const u16* xp = x + ((size_t)(b * Nn + n)) * 3;
    float x0v = b2f(xp[0]), x1v = b2f(xp[1]), x2v = b2f(xp[2]);
    float wv = b2f(wn[b * Nn + n]);
    u16 hb[32] __attribute__((aligned(16)));
    #pragma unroll
    for (int j = 0; j < 32; j++) {
        int c = cp * 32 + j;
        float acc = b2f(fc0_b[c]);
        acc += x0v * b2f(fc0_w[0 * Cc + c]);
        acc += x1v * b2f(fc0_w[1 * Cc + c]);
        acc += x2v * b2f(fc0_w[2 * Cc + c]);
        hb[j] = f2b(acc);
        hw_cn[((size_t)(b * Cc + c)) * Nn + n] = f2b(acc * wv);
    }
    u16* row = hA + ((size_t)b * Nn + n) * 128 + cp * 32;
    #pragma unroll
    for (int i = 0; i < 4; i++) *(uint4*)(row + i * 8) = *(const uint4*)(hb + i * 8);
}

// one-shot all layers: wcT/wsT[l][k][o][i] bf16 from raw [l][i][o][k]; w0T[l][o][i]
__global__ __launch_bounds__(256) void transpose_w(
    const void* __restrict__ wcraw, const void* __restrict__ wsraw,
    const u16* __restrict__ w0n,
    u16* __restrict__ wcT, u16* __restrict__ wsT, u16* __restrict__ w0T,
    const int* __restrict__ flag) {
    __shared__ u16 tile[128][136];
    int o = blockIdx.x, l = blockIdx.y, t = threadIdx.x;
    const int f = *flag;
    if (o == 128) {
        int i = t >> 1, oh = (t & 1) * 64;
        #pragma unroll
        for (int j = 0; j < 64; j += 8)
            *(uint4*)&tile[i][oh + j] = *(const uint4*)(w0n + ((size_t)(l * 128 + i)) * 128 + oh + j);
        __syncthreads();
        int o2 = t >> 1, ih = (t & 1) * 64;
        u16 buf[64] __attribute__((aligned(16)));
        #pragma unroll
        for (int j = 0; j < 64; j++) buf[j] = tile[ih + j][o2];
        #pragma unroll
        for (int j = 0; j < 64; j += 8)
            *(uint4*)(w0T + ((size_t)(l * 128 + o2)) * 128 + ih + j) = *(const uint4*)(buf + j);
        return;
    }
    for (int wsel = 0; wsel < 2; wsel++) {
        if (wsel) __syncthreads();
        const void* raw = wsel ? wsraw : wcraw;
        u16* dst = wsel ? wsT : wcT;
        int i = t >> 1, kh = (t & 1) * 64;
        size_t base = (((size_t)(l * 128 + i)) * 128 + o) * 128 + kh;
        if (f) {
            #pragma unroll
            for (int j = 0; j < 64; j += 8)
                *(uint4*)&tile[i][kh + j] = *(const uint4*)((const u16*)raw + base + j);
        } else {
            #pragma unroll
            for (int j = 0; j < 64; j += 4) {
                float4 v = *(const float4*)((const float*)raw + base + j);
                u16 o4[4] __attribute__((aligned(8))) = { f2b(v.x), f2b(v.y), f2b(v.z), f2b(v.w) };
                *(unsigned long long*)&tile[i][kh + j] = *(const unsigned long long*)o4;
            }
        }
        __syncthreads();
        int k = t >> 1, ih = (t & 1) * 64;
        u16 buf[64] __attribute__((aligned(16)));
        #pragma unroll
        for (int j = 0; j < 64; j++) buf[j] = tile[ih + j][k];
        #pragma unroll
        for (int j = 0; j < 64; j += 8)
            *(uint4*)(dst + (((size_t)(l * 128 + k)) * 128 + o) * 128 + ih + j) = *(const uint4*)(buf + j);
    }
}

// x0[b,c] = sum_n hw[b,c,n]*mask[b,n]
__global__ __launch_bounds__(256) void x0_kernel(
    const u16* __restrict__ hw, const u16* __restrict__ mask,
    float* __restrict__ x0, u16* __restrict__ x0b) {
    int c = blockIdx.x, b = blockIdx.y;
    const u16* row = hw + ((size_t)(b * Cc + c)) * Nn;
    const u16* mrow = mask + (size_t)b * Nn;
    float acc = 0.f;
    for (int n = threadIdx.x; n < Nn; n += 256) acc += b2f(row[n]) * b2f(mrow[n]);
    __shared__ float red[4];
    for (int off = 32; off; off >>= 1) acc += __shfl_down(acc, off, 64);
    if ((threadIdx.x & 63) == 0) red[threadIdx.x >> 6] = acc;
    __syncthreads();
    if (threadIdx.x == 0) {
        float v = red[0] + red[1] + red[2] + red[3];
        x0[b * Cc + c] = v;
        x0b[b * Cc + c] = f2b(v);
    }
}

// MFMA projection v5: grid (32, 4, 8) = 1024 blocks (4/CU).
// Wave w: mode tile = kh*32 + (w&1)*16, c half = (w>>1)*64.
__global__ __launch_bounds__(256) void proj_mfma(
    const u16* __restrict__ hw, const u16* __restrict__ nodes,
    const u16* __restrict__ modes, const u16* __restrict__ mask,
    u16* __restrict__ pxc, u16* __restrict__ pps) {
    int s = blockIdx.x, kh = blockIdx.y, b = blockIdx.z;
    int w = threadIdx.x >> 6, lane = threadIdx.x & 63;
    int lo = lane & 15, q = lane >> 4;
    int n0 = s * 512;
    int kmode = kh * 32 + (w & 1) * 16 + lo;
    int ch = w >> 1;
    float m0 = b2f(modes[kmode * 2]), m1 = b2f(modes[kmode * 2 + 1]);
    const u16* ap[4];
    #pragma unroll
    for (int ct = 0; ct < 4; ct++)
        ap[ct] = hw + ((size_t)(b * Cc) + ch * 64 + ct * 16 + lo) * Nn + n0 + q * 8;
    const u16* np = nodes + ((size_t)(b * Nn) + n0 + q * 8) * 2;
    const u16* mp = mask + (size_t)b * Nn + n0 + q * 8;
    f4 aC[4] = {}, aS[4] = {};
    for (int js = 0; js < 16; js++) {
        int off = js * 32;
        uint4 nq0 = *(const uint4*)(np + off * 2);
        uint4 nq1 = *(const uint4*)(np + off * 2 + 8);
        uint4 mq  = *(const uint4*)(mp + off);
        float xs[8], ys[8], mk[8];
        xs[0] = b2f(nq0.x & 0xffffu); ys[0] = b2f(nq0.x >> 16);
        xs[1] = b2f(nq0.y & 0xffffu); ys[1] = b2f(nq0.y >> 16);
        xs[2] = b2f(nq0.z & 0xffffu); ys[2] = b2f(nq0.z >> 16);
        xs[3] = b2f(nq0.w & 0xffffu); ys[3] = b2f(nq0.w >> 16);
        xs[4] = b2f(nq1.x & 0xffffu); ys[4] = b2f(nq1.x >> 16);
        xs[5] = b2f(nq1.y & 0xffffu); ys[5] = b2f(nq1.y >> 16);
        xs[6] = b2f(nq1.z & 0xffffu); ys[6] = b2f(nq1.z >> 16);
        xs[7] = b2f(nq1.w & 0xffffu); ys[7] = b2f(nq1.w >> 16);
        mk[0] = b2f(mq.x & 0xffffu);  mk[1] = b2f(mq.x >> 16);
        mk[2] = b2f(mq.y & 0xffffu);  mk[3] = b2f(mq.y >> 16);
        mk[4] = b2f(mq.z & 0xffffu);  mk[5] = b2f(mq.z >> 16);
        mk[6] = b2f(mq.w & 0xffffu);  mk[7] = b2f(mq.w >> 16);
        u16 cf[8] __attribute__((aligned(16)));
        u16 sf[8] __attribute__((aligned(16)));
        #pragma unroll
        for (int j = 0; j < 8; j++) {
            float tt = xs[j] * m0 + ys[j] * m1;
            cf[j] = f2b(__cosf(tt) * mk[j]);
            sf[j] = f2b(__sinf(tt) * mk[j]);
        }
        bf8 cv = *(const bf8*)cf;
        bf8 sv = *(const bf8*)sf;
        #pragma unroll
        for (int ct = 0; ct < 4; ct++) {
            bf8 av = *(const bf8*)(ap[ct] + off);
            aC[ct] = __builtin_amdgcn_mfma_f32_16x16x32_bf16(av, cv, aC[ct], 0, 0, 0);
            aS[ct] = __builtin_amdgcn_mfma_f32_16x16x32_bf16(av, sv, aS[ct], 0, 0, 0);
        }
    }
    size_t base = ((size_t)(b * SPLIT + s)) * 16384 + (size_t)kmode * 128;
    #pragma unroll
    for (int ct = 0; ct < 4; ct++) {
        int c0 = ch * 64 + ct * 16 + q * 4;
        u16 pc[4] __attribute__((aligned(8)));
        u16 pssv[4] __attribute__((aligned(8)));
        #pragma unroll
        for (int r = 0; r < 4; r++) { pc[r] = f2b(aC[ct][r]); pssv[r] = f2b(aS[ct][r]); }
        *(uint2*)&pxc[base + c0] = *(const uint2*)pc;
        *(uint2*)&pps[base + c0] = *(const uint2*)pssv;
    }
}

// sum bf16 partials over s -> bf16 xcT/psT [b][k][c]
__global__ __launch_bounds__(256) void reduce_kernel(
    const u16* __restrict__ pxc, const u16* __restrict__ pps,
    u16* __restrict__ xcT, u16* __restrict__ psT) {
    int g = blockIdx.x * 256 + threadIdx.x;
    int b = g >> 14, r = g & 16383;
    const u16* p1 = pxc + ((size_t)b * SPLIT) * 16384 + r;
    const u16* p2 = pps + ((size_t)b * SPLIT) * 16384 + r;
    float a1 = 0.f, a2 = 0.f;
    #pragma unroll
    for (int s2 = 0; s2 < SPLIT; s2++) {
        a1 += b2f(p1[(size_t)s2 * 16384]);
        a2 += b2f(p2[(size_t)s2 * 16384]);
    }
    xcT[g] = f2b(a1); psT[g] = f2b(a2);
}

// MFMA mix: per mode k, U[16][i]=[xc(b);ps(b)], -> Ablk (+f0 block kb==128)
__global__ __launch_bounds__(256) void mix_mfma(
    const u16* __restrict__ xcT, const u16* __restrict__ psT,
    const u16* __restrict__ wcT, const u16* __restrict__ wsT,
    const u16* __restrict__ w0T, const u16* __restrict__ x0b,
    u16* __restrict__ Ablk, float* __restrict__ f0p, int l) {
    int kb = blockIdx.x;
    int w = threadIdx.x >> 6, lane = threadIdx.x & 63;
    int lo = lane & 15, q = lane >> 4;
    if (kb == 128) {
        const u16* Arow = x0b + (lo & 7) * 128 + q * 8;
        f4 acc[2] = {};
        #pragma unroll
        for (int step = 0; step < 4; step++) {
            bf8 av = *(const bf8*)(Arow + step * 32);
            #pragma unroll
            for (int nt = 0; nt < 2; nt++) {
                int o = w * 32 + nt * 16 + lo;
                bf8 bv = *(const bf8*)(w0T + ((size_t)(l * 128 + o)) * 128 + q * 8 + step * 32);
                acc[nt] = __builtin_amdgcn_mfma_f32_16x16x32_bf16(av, bv, acc[nt], 0, 0, 0);
            }
        }
        if (q < 2) {
            #pragma unroll
            for (int nt = 0; nt < 2; nt++)
                #pragma unroll
                for (int r = 0; r < 4; r++) {
                    int bb = q * 4 + r, o = w * 32 + nt * 16 + lo;
                    f0p[bb * 128 + o] = acc[nt][r];
                }
        }
        return;
    }
    int k = kb;
    const u16* Arow = (lo < 8)
        ? xcT + ((size_t)(lo * 128 + k)) * 128 + q * 8
        : psT + ((size_t)((lo - 8) * 128 + k)) * 128 + q * 8;
    const u16* wc_l = wcT + ((size_t)(l * 128 + k)) * (128 * 128);
    const u16* ws_l = wsT + ((size_t)(l * 128 + k)) * (128 * 128);
    f4 accC[2] = {}, accS[2] = {};
    #pragma unroll
    for (int step = 0; step < 4; step++) {
        bf8 av = *(const bf8*)(Arow + step * 32);
        #pragma unroll
        for (int nt = 0; nt < 2; nt++) {
            int o = w * 32 + nt * 16 + lo;
            bf8 bc = *(const bf8*)(wc_l + (size_t)o * 128 + q * 8 + step * 32);
            bf8 bs = *(const bf8*)(ws_l + (size_t)o * 128 + q * 8 + step * 32);
            accC[nt] = __builtin_amdgcn_mfma_f32_16x16x32_bf16(av, bc, accC[nt], 0, 0, 0);
            accS[nt] = __builtin_amdgcn_mfma_f32_16x16x32_bf16(av, bs, accS[nt], 0, 0, 0);
        }
    }
    #pragma unroll
    for (int nt = 0; nt < 2; nt++)
        #pragma unroll
        for (int r = 0; r < 4; r++) {
            float uc = accC[nt][r], us = accS[nt][r];
            float ucp = __shfl_xor(uc, 32, 64);
            float usp = __shfl_xor(us, 32, 64);
            if (q < 2) {
                int bb = q * 4 + r, o = w * 32 + nt * 16 + lo;
                float fcv = uc + usp;
                float fsv = us - ucp;
                Ablk[(((size_t)(bb * 12 + (k >> 5))) * 128 + o) * 32 + (k & 31)] = f2b(2.f * fcv);
                Ablk[(((size_t)(bb * 12 + 4 + (k >> 5))) * 128 + o) * 32 + (k & 31)] = f2b(-2.f * fsv);
            }
        }
}

// fill Ablk conv segment (ks 8..11)
__global__ __launch_bounds__(256) void conv_fill(
    const u16* __restrict__ conv_w, u16* __restrict__ Ablk, int l) {
    int ks2 = blockIdx.x, b = blockIdx.y, t = threadIdx.x;
    int o = t >> 1, half = t & 1;
    const u16* src = conv_w + ((size_t)(l * 128 + o)) * 128 + ks2 * 32 + half * 16;
    u16* dst = Ablk + (((size_t)(b * 12 + 8 + ks2)) * 128 + o) * 32 + half * 16;
    *(uint4*)dst = *(const uint4*)src;
    *(uint4*)(dst + 8) = *(const uint4*)(src + 8);
}

// Ablk1[ks(4)][o(128)][32] = fc1_w^T
__global__ __launch_bounds__(256) void buildA1_blk(
    const u16* __restrict__ fc1_w, u16* __restrict__ Ablk1) {
    int ks = blockIdx.x, t = threadIdx.x;
    int o = t >> 1, half = t & 1;
    u16 ov[16] __attribute__((aligned(16)));
    #pragma unroll
    for (int j = 0; j < 16; j++) {
        int kk = ks * 32 + half * 16 + j;
        ov[j] = fc1_w[kk * 128 + o];
    }
    u16* dst = Ablk1 + ((size_t)ks * 128 + o) * 32 + half * 16;
    *(uint4*)dst = *(const uint4*)ov;
    *(uint4*)(dst + 8) = *(const uint4*)(ov + 8);
}

// MFMA combine v5: LDS-staged GEMM, in-place h update.
// Block 128o x 128n, 4 waves of 64o x 64n, double-buffered LDS tiles.
// EPI 0: gelu, write h (in place) + hw_cn. EPI 1: no gelu, h only. EPI 2: fc1+fc2 -> psum.
template <int EPI, int NKS>
__global__ __launch_bounds__(256) void combine_mfma(
    const u16* __restrict__ Ablk, long astr,
    const u16* __restrict__ bigB, u16* __restrict__ h,
    u16* __restrict__ hw_cn,
    const float* __restrict__ f0p, const u16* __restrict__ bias,
    const u16* __restrict__ mask, const u16* __restrict__ wn,
    const u16* __restrict__ fc2w, float* __restrict__ psum) {
    __shared__ u16 lds[20480];   // 40 KB
    int b = blockIdx.y;
    int nb = blockIdx.x * 128;
    int t = threadIdx.x;
    int w = t >> 6, lane = t & 63;
    int lo = lane & 15, q = lane >> 4;
    int wo = (w & 1) * 64, wn2 = (w >> 1) * 64;

    u16* abuf[2] = { lds, lds + 5120 };
    u16* bbuf[2] = { lds + 10240, lds + 15360 };

    const u16* Ab = Ablk + (size_t)b * astr;
    int so = t >> 1, sh = t & 1;
    size_t brow = (size_t)b * Nn + nb + so;
    const u16* bigRow = bigB + brow * 256 + sh * 16;
    const u16* hRow   = h    + brow * 128 + sh * 16;

    uint4 ra0, ra1, rb0, rb1;
    auto loadGlob = [&](int ksn, uint4& a0, uint4& a1, uint4& b0, uint4& b1) {
        const u16* asrc = Ab + (size_t)ksn * 4096 + so * 32 + sh * 16;
        a0 = *(const uint4*)asrc;
        a1 = *(const uint4*)(asrc + 8);
        const u16* bsrc;
        if (EPI == 2) bsrc = hRow + ksn * 32;
        else bsrc = (ksn < 8) ? (bigRow + ksn * 32) : (hRow + (ksn - 8) * 32);
        b0 = *(const uint4*)bsrc;
        b1 = *(const uint4*)(bsrc + 8);
    };
    auto stash = [&](int pb, uint4 a0, uint4 a1, uint4 b0, uint4 b1) {
        u16* ad = abuf[pb] + so * 40 + sh * 16;
        *(uint4*)ad = a0; *(uint4*)(ad + 8) = a1;
        u16* bd = bbuf[pb] + so * 40 + sh * 16;
        *(uint4*)bd = b0; *(uint4*)(bd + 8) = b1;
    };

    loadGlob(0, ra0, ra1, rb0, rb1);
    stash(0, ra0, ra1, rb0, rb1);
    f4 acc[4][4] = {};
    #pragma unroll
    for (int ks = 0; ks < NKS; ks++) {
        __syncthreads();
        if (ks + 1 < NKS) loadGlob(ks + 1, ra0, ra1, rb0, rb1);
        int pb = ks & 1;
        bf8 avf[4], bvf[4];
        #pragma unroll
        for (int ot = 0; ot < 4; ot++)
            avf[ot] = *(const bf8*)(abuf[pb] + (wo + ot * 16 + lo) * 40 + q * 8);
        #pragma unroll
        for (int nt = 0; nt < 4; nt++)
            bvf[nt] = *(const bf8*)(bbuf[pb] + (wn2 + nt * 16 + lo) * 40 + q * 8);
        #pragma unroll
        for (int ot = 0; ot < 4; ot++)
            #pragma unroll
            for (int nt = 0; nt < 4; nt++)
                acc[ot][nt] = __builtin_amdgcn_mfma_f32_16x16x32_bf16(avf[ot], bvf[nt], acc[ot][nt], 0, 0, 0);
        if (ks + 1 < NKS) stash(1 - pb, ra0, ra1, rb0, rb1);
    }
    __syncthreads();

    if (EPI == 2) {
        #pragma unroll
        for (int nt = 0; nt < 4; nt++) {
            int n = nb + wn2 + nt * 16 + lo;
            float s = 0.f;
            #pragma unroll
            for (int ot = 0; ot < 4; ot++)
                #pragma unroll
                for (int r = 0; r < 4; r++) {
                    int o = wo + ot * 16 + q * 4 + r;
                    float v = acc[ot][nt][r] + b2f(bias[o]);
                    v = gelu_f(v);
                    s += b2f(fc2w[o]) * v;
                }
            s += __shfl_xor(s, 16, 64);
            s += __shfl_xor(s, 32, 64);
            if (q == 0)
                psum[(size_t)(w & 1) * (Bb * Nn) + (size_t)b * Nn + n] = s;
        }
    } else {
        u16* tile = lds + w * 4352;   // 64n x 68 pitch
        #pragma unroll
        for (int nt = 0; nt < 4; nt++) {
            int n = nb + wn2 + nt * 16 + lo;
            float mv = b2f(mask[(size_t)b * Nn + n]);
            #pragma unroll
            for (int ot = 0; ot < 4; ot++) {
                u16 hv[4] __attribute__((aligned(8)));
                #pragma unroll
                for (int r = 0; r < 4; r++) {
                    int o = wo + ot * 16 + q * 4 + r;
                    float v = acc[ot][nt][r] + b2f(bias[o]) + f0p[b * Cc + o] * mv;
                    if (EPI == 0) v = gelu_f(v);
                    hv[r] = f2b(v);
                }
                *(uint2*)&tile[(nt * 16 + lo) * 68 + ot * 16 + q * 4] = *(const uint2*)hv;
            }
        }
        __syncthreads();
        #pragma unroll
        for (int it = 0; it < 8; it++) {
            int row = it * 8 + (lane >> 3), seg = lane & 7;
            uint4 v4 = *(const uint4*)&tile[row * 68 + seg * 8];
            *(uint4*)&h[((size_t)b * Nn + nb + wn2 + row) * 128 + wo + seg * 8] = v4;
        }
        if (EPI == 0) {
            // emit hw_cn[c][n] from the wave's 64n x 64o tile (c = wo+lane)
            int c = wo + lane;
            const u16* wnp = wn + (size_t)b * Nn + nb + wn2;
            u16* dstp = hw_cn + ((size_t)(b * Cc) + c) * Nn + nb + wn2;
            #pragma unroll
            for (int i = 0; i < 8; i++) {
                u16 hv8[8] __attribute__((aligned(16)));
                #pragma unroll
                for (int j2 = 0; j2 < 8; j2++) {
                    int nl2 = i * 8 + j2;
                    hv8[j2] = f2b(b2f(tile[nl2 * 68 + lane]) * b2f(wnp[nl2]));
                }
                *(uint4*)(dstp + i * 8) = *(const uint4*)hv8;
            }
        }
    }
}

// out = (psum0 + psum1 + fc2_b) * mask, dtype per flag
__global__ __launch_bounds__(256) void fc2_final(
    const float* __restrict__ psum, const u16* __restrict__ fc2b,
    const u16* __restrict__ mask, void* __restrict__ out, const int* __restrict__ flag) {
    int g = blockIdx.x * 256 + threadIdx.x;   // < Bb*Nn
    float s = psum[g] + psum[(size_t)Bb * Nn + g] + b2f(fc2b[0]);
    s *= b2f(mask[g]);
    if (*flag) ((u16*)out)[g] = f2b(s);
    else       ((float*)out)[g] = s;
}

extern "C" void kernel_launch(void* const* d_in, const int* in_sizes, int n_in,
                              void* d_out, int out_size, void* d_ws, size_t ws_size,
                              hipStream_t stream) {
    char* p = (char*)d_ws;
    auto alloc = [&](size_t bytes) { void* r = (void*)p; p += (bytes + 255) & ~(size_t)255; return r; };

    int* flag = (int*)alloc(256);

    SegTable tab;
    u16* nin[16];
    for (int i = 0; i < 16; i++) {
        tab.src[i] = d_in[i];
        if (i == 7 || i == 8) {
            nin[i] = (u16*)flag;
            tab.dst[i] = nin[i];
            tab.count[i] = 0;
        } else {
            int cnt = in_sizes[i];
            nin[i] = (u16*)alloc((size_t)cnt * 2);
            tab.dst[i] = nin[i];
            tab.count[i] = cnt;
        }
    }
    const u16* x      = nin[0];
    const u16* nodes  = nin[1];
    const u16* mask   = nin[2];
    const u16* wn     = nin[3];
    const u16* modes  = nin[4];
    const u16* fc0_w  = nin[5];
    const u16* fc0_b  = nin[6];
    const u16* w0n    = nin[9];
    const u16* conv_w = nin[10];
    const u16* conv_b = nin[11];
    const u16* fc1_w  = nin[12];
    const u16* fc1_b  = nin[13];
    const u16* fc2_w  = nin[14];
    const u16* fc2_b  = nin[15];

    u16* bigB   = (u16*)alloc((size_t)Bb * Nn * 256 * 2);        // 67.1 MB
    u16* hA     = (u16*)alloc((size_t)Bb * Nn * 128 * 2);        // 33.6 MB
    u16* hw_cn  = (u16*)alloc((size_t)Bb * Cc * Nn * 2);         // 33.6 MB
    u16* pxc    = (u16*)alloc((size_t)Bb * SPLIT * Cc * Kk * 2); // 8.4 MB
    u16* pps    = (u16*)alloc((size_t)Bb * SPLIT * Cc * Kk * 2); // 8.4 MB
    u16* wcT    = (u16*)alloc((size_t)Ll * Kk * Cc * Cc * 2);    // 16.8 MB
    u16* wsT    = (u16*)alloc((size_t)Ll * Kk * Cc * Cc * 2);    // 16.8 MB
    u16* w0T    = (u16*)alloc((size_t)Ll * Cc * Cc * 2);
    u16* xcT    = (u16*)alloc((size_t)Bb * Kk * Cc * 2);
    u16* psT    = (u16*)alloc((size_t)Bb * Kk * Cc * 2);
    float* x0f  = (float*)alloc((size_t)Bb * Cc * 4);
    u16* x0b    = (u16*)alloc((size_t)Bb * Cc * 2);
    float* f0f  = (float*)alloc((size_t)Bb * Cc * 4);
    u16* Ablk   = (u16*)alloc((size_t)Bb * 12 * 128 * 32 * 2);
    u16* Ablk1  = (u16*)alloc((size_t)4 * 128 * 32 * 2);
    float* psum = (float*)alloc((size_t)2 * Bb * Nn * 4);        // 1.0 MB
    // total ws ~= 190 MB

    const long ASTR = 12L * 128 * 32;

    detect_kernel<<<1, 64, 0, stream>>>((const unsigned int*)d_in[2], flag);
    convert_kernel<<<512, 256, 0, stream>>>(tab, flag);

    transpose_w<<<dim3(129, Ll), 256, 0, stream>>>(d_in[7], d_in[8], w0n, wcT, wsT, w0T, flag);
    bases_nk_kernel<<<dim3(Nn / 64, Bb), 256, 0, stream>>>(nodes, modes, mask, bigB);
    fc0_nk_kernel<<<dim3(Nn / 64, Bb), 256, 0, stream>>>(x, fc0_w, fc0_b, wn, hA, hw_cn);

    for (int l = 0; l < Ll; l++) {
        x0_kernel<<<dim3(Cc, Bb), 256, 0, stream>>>(hw_cn, mask, x0f, x0b);
        proj_mfma<<<dim3(SPLIT, 4, Bb), 256, 0, stream>>>(hw_cn, nodes, modes, mask, pxc, pps);
        reduce_kernel<<<dim3((Bb * Cc * Kk) / 256), 256, 0, stream>>>(pxc, pps, xcT, psT);
        conv_fill<<<dim3(4, Bb), 256, 0, stream>>>(conv_w, Ablk, l);
        mix_mfma<<<dim3(129), 256, 0, stream>>>(xcT, psT, wcT, wsT, w0T, x0b, Ablk, f0f, l);
        if (l < Ll - 1) {
            combine_mfma<0, 12><<<dim3(Nn / 128, Bb), 256, 0, stream>>>(
                Ablk, ASTR, bigB, hA, hw_cn, f0f, conv_b + l * Cc, mask, wn, fc2_w, psum);
        } else {
            combine_mfma<1, 12><<<dim3(Nn / 128, Bb), 256, 0, stream>>>(
                Ablk, ASTR, bigB, hA, hw_cn, f0f, conv_b + l * Cc, mask, wn, fc2_w, psum);
        }
    }

    buildA1_blk<<<dim3(4), 256, 0, stream>>>(fc1_w, Ablk1);
    combine_mfma<2, 4><<<dim3(Nn / 128, Bb), 256, 0, stream>>>(
        Ablk1, 0L, bigB, hA, hw_cn, f0f, fc1_b, mask, wn, fc2_w, psum);
    fc2_final<<<dim3((Bb * Nn) / 256), 256, 0, stream>>>(psum, fc2_b, mask, d_out, flag);
}